// Round 3
// baseline (285.608 us; speedup 1.0000x reference)
//
#include <hip/hip_runtime.h>
#include <hip/hip_fp16.h>

// GAT (2 layers, heads=1) + 2-layer MLP head. N=100000, E=3200000, D=128.
// R18 = R17 front fusion (TILE back to 8192 to restore run lengths / write
// amp) + restructured agg gather: 2 lanes x 16B loads per node instead of
// 4 lanes x 8B. The 4 lanes per node split into two 2-lane subgroups, each
// aggregating half of the node's edge list; halves combined via shfl_xor.
// Halves scattered VMEM addresses per edge (4->2) and gather instruction
// count (~2x). Overflow -> full-rescan fallback keeps arbitrary inputs
// correct. Softmax stabilization uses a GLOBAL upper bound
// m̄_i = leaky(gmax_asrc + adst_i) (valid since leaky_relu is monotone).

#define NEG 0.2f
#define FSH 7
#define BNODES 128           // nodes per bucket
#define NSBMAX 1024          // >= ceil(100000/128)=782
#define CAPB 4608            // per-bucket region capacity (mean 4096, +8 sigma)
#define TILE 8192            // edges per csplit block (256 threads, 32 iters)
#define PES 9                // ceil(CAPB/512) register-staged pairs per thread

__device__ __forceinline__ float lrelu(float x) { return x > 0.0f ? x : NEG * x; }

__device__ __forceinline__ unsigned fenc(float f) {
    unsigned u = __float_as_uint(f);
    return (u & 0x80000000u) ? ~u : (u | 0x80000000u);
}
__device__ __forceinline__ float fdec(unsigned e) {
    return (e & 0x80000000u) ? __uint_as_float(e & 0x7FFFFFFFu) : __uint_as_float(~e);
}

// load 4 consecutive halves as float4 (8B load)
__device__ __forceinline__ float4 ldh4(const __half* h, size_t off) {
    uint2 u = *(const uint2*)(h + off);
    __half2 a = *(__half2*)&u.x, b = *(__half2*)&u.y;
    float2 fa = __half22float2(a), fb = __half22float2(b);
    return make_float4(fa.x, fa.y, fb.x, fb.y);
}

// load 8 consecutive halves as two float4 (single 16B load)
__device__ __forceinline__ void ldh8(const __half* h, size_t off, float4& a, float4& b) {
    uint4 u = *(const uint4*)(h + off);
    __half2 p0 = *(__half2*)&u.x, p1 = *(__half2*)&u.y;
    __half2 p2 = *(__half2*)&u.z, p3 = *(__half2*)&u.w;
    float2 f0 = __half22float2(p0), f1 = __half22float2(p1);
    float2 f2 = __half22float2(p2), f3 = __half22float2(p3);
    a = make_float4(f0.x, f0.y, f1.x, f1.y);
    b = make_float4(f2.x, f2.y, f3.x, f3.y);
}

// ---- fused front-end: gemm role + csplit role in one grid ----
__global__ __launch_bounds__(256) void k_front(
    const float* __restrict__ x, const float* __restrict__ W1,
    const float* __restrict__ a1s, const float* __restrict__ a1d,
    __half* __restrict__ h1, float* __restrict__ s1, float* __restrict__ d1,
    unsigned* __restrict__ gmax,
    const int* __restrict__ esrc, const int* __restrict__ edst,
    int* __restrict__ bcur, unsigned* __restrict__ pairs,
    int N, int E, int NG, int NC, int NSB)
{
    // union LDS: gemm 2048 + 64*132 + 4 = 10500 words
    //            csplit TILE + 3*NSBMAX + 4 = 11268 words
    __shared__ float smem[11268];
    int tid = threadIdx.x;
    int bid = blockIdx.x;
    long long T = (long long)NG + NC;
    int before = (int)(((long long)bid * NC) / T);       // csplit blocks before bid
    int isc = (int)((((long long)bid + 1) * NC) / T) > before;

    if (isc) {
        // ------------------ csplit role ------------------
        unsigned* lsrt = (unsigned*)smem;           // TILE
        int* lhist = (int*)smem + TILE;             // NSBMAX
        int* lofs  = lhist + NSBMAX;                // NSBMAX
        int* gbase = lofs + NSBMAX;                 // NSBMAX
        int* wsum  = gbase + NSBMAX;                // 4
        int cid = before;
        int base = cid * TILE;
        int tcnt = min(TILE, E - base);
        for (int i = tid; i < NSB; i += 256) lhist[i] = 0;
        __syncthreads();
        for (int i = tid; i < tcnt; i += 256)
            atomicAdd(&lhist[edst[base + i] >> FSH], 1);
        __syncthreads();
        // 4 keys per thread scan (NSB <= 1024 = 4*256)
        int i0 = 4 * tid;
        int a0 = (i0 + 0 < NSB) ? lhist[i0 + 0] : 0;
        int a1 = (i0 + 1 < NSB) ? lhist[i0 + 1] : 0;
        int a2 = (i0 + 2 < NSB) ? lhist[i0 + 2] : 0;
        int a3 = (i0 + 3 < NSB) ? lhist[i0 + 3] : 0;
        int s = a0 + a1 + a2 + a3, pfx = s;
#pragma unroll
        for (int off = 1; off < 64; off <<= 1) {
            int t = __shfl_up(pfx, off, 64);
            if ((tid & 63) >= off) pfx += t;
        }
        if ((tid & 63) == 63) wsum[tid >> 6] = pfx;
        __syncthreads();
        int carry = 0;
        for (int w = 0; w < (tid >> 6); ++w) carry += wsum[w];
        int excl = pfx + carry - s;
        if (i0 + 0 < NSB) { lofs[i0 + 0] = excl;                 gbase[i0 + 0] = a0 ? atomicAdd(&bcur[(i0 + 0) * 16], a0) : 0; }
        if (i0 + 1 < NSB) { lofs[i0 + 1] = excl + a0;            gbase[i0 + 1] = a1 ? atomicAdd(&bcur[(i0 + 1) * 16], a1) : 0; }
        if (i0 + 2 < NSB) { lofs[i0 + 2] = excl + a0 + a1;       gbase[i0 + 2] = a2 ? atomicAdd(&bcur[(i0 + 2) * 16], a2) : 0; }
        if (i0 + 3 < NSB) { lofs[i0 + 3] = excl + a0 + a1 + a2;  gbase[i0 + 3] = a3 ? atomicAdd(&bcur[(i0 + 3) * 16], a3) : 0; }
        __syncthreads();
        if (i0 + 0 < NSB) lhist[i0 + 0] = lofs[i0 + 0];   // cursors
        if (i0 + 1 < NSB) lhist[i0 + 1] = lofs[i0 + 1];
        if (i0 + 2 < NSB) lhist[i0 + 2] = lofs[i0 + 2];
        if (i0 + 3 < NSB) lhist[i0 + 3] = lofs[i0 + 3];
        __syncthreads();
        for (int i = tid; i < tcnt; i += 256) {
            int e = base + i;
            int d = edst[e], srcv = esrc[e];
            int pos = atomicAdd(&lhist[d >> FSH], 1);
            lsrt[pos] = ((unsigned)(d & (BNODES - 1)) << 17) | (unsigned)srcv;
        }
        __syncthreads();
        // flattened flush: binary search run id, coalesced run-contiguous stores
        for (int i = tid; i < tcnt; i += 256) {
            int lo = 0, hi = NSB - 1;
            while (lo < hi) { int mid = (lo + hi + 1) >> 1; if (lofs[mid] <= i) lo = mid; else hi = mid - 1; }
            int rel = gbase[lo] + (i - lofs[lo]);
            if (rel < CAPB) pairs[(size_t)lo * CAPB + rel] = lsrt[i];
        }
        return;
    }

    // ------------------ gemm role ------------------
    float* sW = smem;                 // 2048
    float* sx = smem + 2048;          // 64*132
    float* wm = smem + 2048 + 64 * 132; // 4
    int gid = bid - before;
    for (int i = tid; i < 2048; i += 256) sW[i] = W1[i];
    int node0 = gid * 64;
    for (int i = tid; i < 64 * 32; i += 256) {
        int row = i >> 5, c4 = i & 31;
        int n = node0 + row;
        float4 v = make_float4(0.f, 0.f, 0.f, 0.f);
        if (n < N) v = ((const float4*)x)[(size_t)n * 32 + c4];
        *(float4*)&sx[row * 132 + c4 * 4] = v;
    }
    __syncthreads();

    int node = node0 + (tid >> 2);
    int grp  = tid & 3;
    const float* xr = &sx[(tid >> 2) * 132];
    float4 acc = make_float4(0.f, 0.f, 0.f, 0.f);
#pragma unroll 8
    for (int j = 0; j < 128; ++j) {
        float xv = xr[j];
        float4 w = *(const float4*)&sW[j * 16 + grp * 4];
        acc.x += xv * w.x; acc.y += xv * w.y; acc.z += xv * w.z; acc.w += xv * w.w;
    }
    float4 as = ((const float4*)a1s)[grp];
    float4 ad = ((const float4*)a1d)[grp];
    float sv = acc.x * as.x + acc.y * as.y + acc.z * as.z + acc.w * as.w;
    float dv = acc.x * ad.x + acc.y * ad.y + acc.z * ad.z + acc.w * ad.w;
    sv += __shfl_xor(sv, 1); sv += __shfl_xor(sv, 2);
    dv += __shfl_xor(dv, 1); dv += __shfl_xor(dv, 2);
    if (node < N) {
        __half2 p0 = __floats2half2_rn(acc.x, acc.y);
        __half2 p1 = __floats2half2_rn(acc.z, acc.w);
        uint2 u; u.x = *(unsigned*)&p0; u.y = *(unsigned*)&p1;
        *(uint2*)&h1[(size_t)node * 16 + grp * 4] = u;
        if (grp == 0) { s1[node] = sv; d1[node] = dv; }
    }
    float m = (node < N) ? sv : -3.4e38f;
#pragma unroll
    for (int off = 32; off >= 1; off >>= 1) m = fmaxf(m, __shfl_xor(m, off));
    if ((tid & 63) == 0) wm[tid >> 6] = m;
    __syncthreads();
    if (tid == 0) {
        float b = fmaxf(fmaxf(wm[0], wm[1]), fmaxf(wm[2], wm[3]));
        atomicMax(gmax, fenc(b));
    }
}

// ---- layer-1 agg: own-region LDS sort + 2-lane/16B split-list gather ----
__global__ __launch_bounds__(512) void k_agg1(
    const int* __restrict__ bcur, const unsigned* __restrict__ pairs,
    const int* __restrict__ esrc, const int* __restrict__ edst,
    const float* __restrict__ s1, const float* __restrict__ d1, const __half* __restrict__ h1,
    const float* __restrict__ b1, const float* __restrict__ W2,
    const float* __restrict__ a2s, const float* __restrict__ a2d,
    __half* __restrict__ h2, float* __restrict__ s2, float* __restrict__ d2,
    const unsigned* __restrict__ gmax1p, unsigned* __restrict__ gmax2, int N, int E)
{
    __shared__ unsigned srt[CAPB];
    __shared__ float accs[BNODES * 17];
    __shared__ int lcnt[BNODES];
    __shared__ int lofs[BNODES + 1];
    __shared__ float dds[BNODES], mbs[BNODES];
    __shared__ float sW[160], sb[16], sas[16], sad[16];
    __shared__ int wsum[8];
    __shared__ float wm[8];

    int tid = threadIdx.x;
    int fb = blockIdx.x;
    if (tid < 160) sW[tid] = W2[tid];
    if (tid < 16) {
        sb[tid]  = b1[tid];
        sas[tid] = (tid < 10) ? a2s[tid] : 0.f;
        sad[tid] = (tid < 10) ? a2d[tid] : 0.f;
    }
    int node0 = fb << FSH;
    float g0 = fdec(*gmax1p);
    if (tid < BNODES) {
        int n = node0 + tid;
        float dd = (n < N) ? d1[n] : 0.f;
        dds[tid] = dd; mbs[tid] = lrelu(g0 + dd);
        lcnt[tid] = 0;
    }
    __syncthreads();

    int rbase = fb * CAPB;
    int cnt = bcur[fb * 16];             // RELATIVE count; > CAPB means overflow
    int gg = tid >> 2, q = tid & 3;      // 128 groups x 4 lanes, 1 node each

    if (cnt <= CAPB) {
        // count pass with register staging (single global read of pairs)
        unsigned pe[PES];
#pragma unroll
        for (int u = 0; u < PES; ++u) {
            int i = tid + u * 512;
            bool ok = (i < cnt);
            pe[u] = ok ? pairs[rbase + i] : 0u;
            if (ok) atomicAdd(&lcnt[(pe[u] >> 17) & (BNODES - 1)], 1);
        }
        __syncthreads();
        // 128-key scan (padded to 512 threads)
        int c = (tid < BNODES) ? lcnt[tid] : 0;
        int pfx = c;
#pragma unroll
        for (int off = 1; off < 64; off <<= 1) {
            int t = __shfl_up(pfx, off, 64);
            if ((tid & 63) >= off) pfx += t;
        }
        if ((tid & 63) == 63) wsum[tid >> 6] = pfx;
        __syncthreads();
        int carry = 0;
        for (int w = 0; w < (tid >> 6); ++w) carry += wsum[w];
        pfx += carry;
        if (tid < BNODES) { lofs[tid + 1] = pfx; lcnt[tid] = pfx - c; }
        if (tid == 0) lofs[0] = 0;
        __syncthreads();
        // scatter pass from registers -> dst-sorted srcs
#pragma unroll
        for (int u = 0; u < PES; ++u) {
            int i = tid + u * 512;
            if (i < cnt) {
                unsigned p = pe[u];
                int pos = atomicAdd(&lcnt[(p >> 17) & (BNODES - 1)], 1);
                srt[pos] = p & 0x1FFFF;
            }
        }
        __syncthreads();

        // gather: 2-lane subgroups (sub = q>>1) each own half the edge list;
        // lane ql covers 8 of 16 cols via one 16B load per edge.
        int n = node0 + gg;
        int sub = q >> 1, ql = q & 1;
        float dd = dds[gg], mb = mbs[gg];
        float4 aA = make_float4(0.f, 0.f, 0.f, 0.f);
        float4 aB = make_float4(0.f, 0.f, 0.f, 0.f);
        float den = 0.f;
        if (n < N && sub == 0) {         // self-loop into sub0 only
            float w = __expf(lrelu(s1[n] + dd) - mb);
            float4 hA, hB; ldh8(h1, (size_t)n * 16 + 8 * ql, hA, hB);
            aA = make_float4(w * hA.x, w * hA.y, w * hA.z, w * hA.w);
            aB = make_float4(w * hB.x, w * hB.y, w * hB.z, w * hB.w);
            den = w;
        }
        {
            int lo = lofs[gg], hi = lofs[gg + 1];
            int half = (hi - lo + 1) >> 1;
            int j  = lo + sub * half;
            int j1 = sub ? hi : lo + half;
            for (; j + 4 <= j1; j += 4) {
                int e0 = srt[j], e1 = srt[j + 1], e2 = srt[j + 2], e3 = srt[j + 3];
                int eA = ql ? e1 : e0, eB = ql ? e3 : e2;
                float wqA = __expf(lrelu(s1[eA] + dd) - mb);
                float wqB = __expf(lrelu(s1[eB] + dd) - mb);
                float w0 = __shfl(wqA, 0, 2), w1 = __shfl(wqA, 1, 2);
                float w2 = __shfl(wqB, 0, 2), w3 = __shfl(wqB, 1, 2);
                float4 H0a, H0b, H1a, H1b, H2a, H2b, H3a, H3b;
                ldh8(h1, (size_t)e0 * 16 + 8 * ql, H0a, H0b);
                ldh8(h1, (size_t)e1 * 16 + 8 * ql, H1a, H1b);
                ldh8(h1, (size_t)e2 * 16 + 8 * ql, H2a, H2b);
                ldh8(h1, (size_t)e3 * 16 + 8 * ql, H3a, H3b);
                aA.x += w0 * H0a.x + w1 * H1a.x + w2 * H2a.x + w3 * H3a.x;
                aA.y += w0 * H0a.y + w1 * H1a.y + w2 * H2a.y + w3 * H3a.y;
                aA.z += w0 * H0a.z + w1 * H1a.z + w2 * H2a.z + w3 * H3a.z;
                aA.w += w0 * H0a.w + w1 * H1a.w + w2 * H2a.w + w3 * H3a.w;
                aB.x += w0 * H0b.x + w1 * H1b.x + w2 * H2b.x + w3 * H3b.x;
                aB.y += w0 * H0b.y + w1 * H1b.y + w2 * H2b.y + w3 * H3b.y;
                aB.z += w0 * H0b.z + w1 * H1b.z + w2 * H2b.z + w3 * H3b.z;
                aB.w += w0 * H0b.w + w1 * H1b.w + w2 * H2b.w + w3 * H3b.w;
                den += (w0 + w1) + (w2 + w3);
            }
            for (; j < j1; ++j) {
                int e0 = srt[j];
                float w0 = __expf(lrelu(s1[e0] + dd) - mb);
                float4 Ha, Hb; ldh8(h1, (size_t)e0 * 16 + 8 * ql, Ha, Hb);
                aA.x += w0 * Ha.x; aA.y += w0 * Ha.y; aA.z += w0 * Ha.z; aA.w += w0 * Ha.w;
                aB.x += w0 * Hb.x; aB.y += w0 * Hb.y; aB.z += w0 * Hb.z; aB.w += w0 * Hb.w;
                den += w0;
            }
        }
        // combine sub halves (lanes q <-> q^2) and stage to LDS
        aA.x += __shfl_xor(aA.x, 2, 4); aA.y += __shfl_xor(aA.y, 2, 4);
        aA.z += __shfl_xor(aA.z, 2, 4); aA.w += __shfl_xor(aA.w, 2, 4);
        aB.x += __shfl_xor(aB.x, 2, 4); aB.y += __shfl_xor(aB.y, 2, 4);
        aB.z += __shfl_xor(aB.z, 2, 4); aB.w += __shfl_xor(aB.w, 2, 4);
        den  += __shfl_xor(den, 2, 4);
        if (sub == 0) {
            int cbase = gg * 17 + 8 * ql;
            accs[cbase + 0] = aA.x; accs[cbase + 1] = aA.y;
            accs[cbase + 2] = aA.z; accs[cbase + 3] = aA.w;
            accs[cbase + 4] = aB.x; accs[cbase + 5] = aB.y;
            accs[cbase + 6] = aB.z; accs[cbase + 7] = aB.w;
            if (q == 0) accs[gg * 17 + 16] = den;
        }
        __syncthreads();
    } else {
        // overflow: region incomplete -> full rescan of source edges (never-path)
        for (int i = tid; i < BNODES * 17; i += 512) accs[i] = 0.f;
        __syncthreads();
        if (tid < BNODES) {
            int n = node0 + tid;
            if (n < N) {
                float w = __expf(lrelu(s1[n] + dds[tid]) - mbs[tid]);
#pragma unroll
                for (int t = 0; t < 16; ++t)
                    accs[tid * 17 + t] = w * __half2float(h1[(size_t)n * 16 + t]);
                accs[tid * 17 + 16] = w;
            }
        }
        __syncthreads();
        for (int i = tid; i < E; i += 512) {
            int d = edst[i];
            if ((d >> FSH) != fb) continue;
            int nl = d & (BNODES - 1), src = esrc[i];
            float w = __expf(lrelu(s1[src] + dds[nl]) - mbs[nl]);
#pragma unroll
            for (int t = 0; t < 16; ++t)
                atomicAdd(&accs[nl * 17 + t], w * __half2float(h1[(size_t)src * 16 + t]));
            atomicAdd(&accs[nl * 17 + 16], w);
        }
        __syncthreads();
    }

    // epilogue: 32 groups of 16 lanes, 4 nodes each
    int g = tid >> 4, k = tid & 15;
    float sval = -3.4e38f;
#pragma unroll
    for (int qq = 0; qq < 4; ++qq) {
        int nl = g * 4 + qq, nn = node0 + nl;
        if (nn >= N) continue;           // group-uniform
        float inv = 1.f / accs[nl * 17 + 16];
        float o = fmaxf(accs[nl * 17 + k] * inv + sb[k], 0.f);
        float hh = 0.f;
#pragma unroll
        for (int kk = 0; kk < 16; ++kk) {
            float ov = __shfl(o, kk, 16);
            if (k < 10) hh += ov * sW[kk * 10 + k];
        }
        if (k >= 10) hh = 0.f;
        float ts = hh * sas[k];
        float td = hh * sad[k];
#pragma unroll
        for (int off = 1; off < 16; off <<= 1) {
            ts += __shfl_xor(ts, off, 16);
            td += __shfl_xor(td, off, 16);
        }
        h2[(size_t)nn * 16 + k] = __float2half_rn(hh);  // zero-padded cols 10..15
        if (k == 0) { s2[nn] = ts; d2[nn] = td; }
        sval = fmaxf(sval, ts);
    }
    float m = sval;
#pragma unroll
    for (int off = 32; off >= 1; off >>= 1) m = fmaxf(m, __shfl_xor(m, off));
    if ((tid & 63) == 0) wm[tid >> 6] = m;
    __syncthreads();
    if (tid == 0) {
        float bmx = wm[0];
#pragma unroll
        for (int i = 1; i < 8; ++i) bmx = fmaxf(bmx, wm[i]);
        atomicMax(gmax2, fenc(bmx));
    }
}

// ---- layer-2 agg (same structure) + norm/bias + MLP head -> out ----
__global__ __launch_bounds__(512) void k_agg2(
    const int* __restrict__ bcur, const unsigned* __restrict__ pairs,
    const int* __restrict__ esrc, const int* __restrict__ edst,
    const float* __restrict__ s2, const float* __restrict__ d2, const __half* __restrict__ h2,
    const float* __restrict__ b2, const float* __restrict__ Wl1, const float* __restrict__ bl1,
    const float* __restrict__ Wl2, const float* __restrict__ bl2,
    const unsigned* __restrict__ gmax2p, float* __restrict__ out, int N, int E)
{
    __shared__ unsigned srt[CAPB];
    __shared__ float accs[BNODES * 17];
    __shared__ int lcnt[BNODES];
    __shared__ int lofs[BNODES + 1];
    __shared__ float dds[BNODES], mbs[BNODES];
    __shared__ float sW1[100], sb1[16], sW2[16], sb2g[16];
    __shared__ float sbl2;
    __shared__ int wsum[8];

    int tid = threadIdx.x;
    int fb = blockIdx.x;
    if (tid < 100) sW1[tid] = Wl1[tid];
    if (tid < 16) {
        sb1[tid]  = (tid < 10) ? bl1[tid] : 0.f;
        sW2[tid]  = (tid < 10) ? Wl2[tid] : 0.f;
        sb2g[tid] = (tid < 10) ? b2[tid]  : 0.f;
    }
    if (tid == 0) sbl2 = bl2[0];
    int node0 = fb << FSH;
    float g0 = fdec(*gmax2p);
    if (tid < BNODES) {
        int n = node0 + tid;
        float dd = (n < N) ? d2[n] : 0.f;
        dds[tid] = dd; mbs[tid] = lrelu(g0 + dd);
        lcnt[tid] = 0;
    }
    __syncthreads();

    int rbase = fb * CAPB;
    int cnt = bcur[fb * 16];             // RELATIVE count
    int gg = tid >> 2, q = tid & 3;

    if (cnt <= CAPB) {
        unsigned pe[PES];
#pragma unroll
        for (int u = 0; u < PES; ++u) {
            int i = tid + u * 512;
            bool ok = (i < cnt);
            pe[u] = ok ? pairs[rbase + i] : 0u;
            if (ok) atomicAdd(&lcnt[(pe[u] >> 17) & (BNODES - 1)], 1);
        }
        __syncthreads();
        int c = (tid < BNODES) ? lcnt[tid] : 0;
        int pfx = c;
#pragma unroll
        for (int off = 1; off < 64; off <<= 1) {
            int t = __shfl_up(pfx, off, 64);
            if ((tid & 63) >= off) pfx += t;
        }
        if ((tid & 63) == 63) wsum[tid >> 6] = pfx;
        __syncthreads();
        int carry = 0;
        for (int w = 0; w < (tid >> 6); ++w) carry += wsum[w];
        pfx += carry;
        if (tid < BNODES) { lofs[tid + 1] = pfx; lcnt[tid] = pfx - c; }
        if (tid == 0) lofs[0] = 0;
        __syncthreads();
#pragma unroll
        for (int u = 0; u < PES; ++u) {
            int i = tid + u * 512;
            if (i < cnt) {
                unsigned p = pe[u];
                int pos = atomicAdd(&lcnt[(p >> 17) & (BNODES - 1)], 1);
                srt[pos] = p & 0x1FFFF;
            }
        }
        __syncthreads();

        int n = node0 + gg;
        int sub = q >> 1, ql = q & 1;
        float dd = dds[gg], mb = mbs[gg];
        float4 aA = make_float4(0.f, 0.f, 0.f, 0.f);
        float4 aB = make_float4(0.f, 0.f, 0.f, 0.f);
        float den = 0.f;
        if (n < N && sub == 0) {
            float w = __expf(lrelu(s2[n] + dd) - mb);
            float4 hA, hB; ldh8(h2, (size_t)n * 16 + 8 * ql, hA, hB);
            aA = make_float4(w * hA.x, w * hA.y, w * hA.z, w * hA.w);
            aB = make_float4(w * hB.x, w * hB.y, w * hB.z, w * hB.w);
            den = w;
        }
        {
            int lo = lofs[gg], hi = lofs[gg + 1];
            int half = (hi - lo + 1) >> 1;
            int j  = lo + sub * half;
            int j1 = sub ? hi : lo + half;
            for (; j + 4 <= j1; j += 4) {
                int e0 = srt[j], e1 = srt[j + 1], e2 = srt[j + 2], e3 = srt[j + 3];
                int eA = ql ? e1 : e0, eB = ql ? e3 : e2;
                float wqA = __expf(lrelu(s2[eA] + dd) - mb);
                float wqB = __expf(lrelu(s2[eB] + dd) - mb);
                float w0 = __shfl(wqA, 0, 2), w1 = __shfl(wqA, 1, 2);
                float w2 = __shfl(wqB, 0, 2), w3 = __shfl(wqB, 1, 2);
                float4 H0a, H0b, H1a, H1b, H2a, H2b, H3a, H3b;
                ldh8(h2, (size_t)e0 * 16 + 8 * ql, H0a, H0b);
                ldh8(h2, (size_t)e1 * 16 + 8 * ql, H1a, H1b);
                ldh8(h2, (size_t)e2 * 16 + 8 * ql, H2a, H2b);
                ldh8(h2, (size_t)e3 * 16 + 8 * ql, H3a, H3b);
                aA.x += w0 * H0a.x + w1 * H1a.x + w2 * H2a.x + w3 * H3a.x;
                aA.y += w0 * H0a.y + w1 * H1a.y + w2 * H2a.y + w3 * H3a.y;
                aA.z += w0 * H0a.z + w1 * H1a.z + w2 * H2a.z + w3 * H3a.z;
                aA.w += w0 * H0a.w + w1 * H1a.w + w2 * H2a.w + w3 * H3a.w;
                aB.x += w0 * H0b.x + w1 * H1b.x + w2 * H2b.x + w3 * H3b.x;
                aB.y += w0 * H0b.y + w1 * H1b.y + w2 * H2b.y + w3 * H3b.y;
                aB.z += w0 * H0b.z + w1 * H1b.z + w2 * H2b.z + w3 * H3b.z;
                aB.w += w0 * H0b.w + w1 * H1b.w + w2 * H2b.w + w3 * H3b.w;
                den += (w0 + w1) + (w2 + w3);
            }
            for (; j < j1; ++j) {
                int e0 = srt[j];
                float w0 = __expf(lrelu(s2[e0] + dd) - mb);
                float4 Ha, Hb; ldh8(h2, (size_t)e0 * 16 + 8 * ql, Ha, Hb);
                aA.x += w0 * Ha.x; aA.y += w0 * Ha.y; aA.z += w0 * Ha.z; aA.w += w0 * Ha.w;
                aB.x += w0 * Hb.x; aB.y += w0 * Hb.y; aB.z += w0 * Hb.z; aB.w += w0 * Hb.w;
                den += w0;
            }
        }
        aA.x += __shfl_xor(aA.x, 2, 4); aA.y += __shfl_xor(aA.y, 2, 4);
        aA.z += __shfl_xor(aA.z, 2, 4); aA.w += __shfl_xor(aA.w, 2, 4);
        aB.x += __shfl_xor(aB.x, 2, 4); aB.y += __shfl_xor(aB.y, 2, 4);
        aB.z += __shfl_xor(aB.z, 2, 4); aB.w += __shfl_xor(aB.w, 2, 4);
        den  += __shfl_xor(den, 2, 4);
        if (sub == 0) {
            int cbase = gg * 17 + 8 * ql;
            accs[cbase + 0] = aA.x; accs[cbase + 1] = aA.y;
            accs[cbase + 2] = aA.z; accs[cbase + 3] = aA.w;
            accs[cbase + 4] = aB.x; accs[cbase + 5] = aB.y;
            accs[cbase + 6] = aB.z; accs[cbase + 7] = aB.w;
            if (q == 0) accs[gg * 17 + 16] = den;
        }
        __syncthreads();
    } else {
        for (int i = tid; i < BNODES * 17; i += 512) accs[i] = 0.f;
        __syncthreads();
        if (tid < BNODES) {
            int n = node0 + tid;
            if (n < N) {
                float w = __expf(lrelu(s2[n] + dds[tid]) - mbs[tid]);
#pragma unroll
                for (int t = 0; t < 16; ++t)
                    accs[tid * 17 + t] = w * __half2float(h2[(size_t)n * 16 + t]);
                accs[tid * 17 + 16] = w;
            }
        }
        __syncthreads();
        for (int i = tid; i < E; i += 512) {
            int d = edst[i];
            if ((d >> FSH) != fb) continue;
            int nl = d & (BNODES - 1), src = esrc[i];
            float w = __expf(lrelu(s2[src] + dds[nl]) - mbs[nl]);
#pragma unroll
            for (int t = 0; t < 16; ++t)
                atomicAdd(&accs[nl * 17 + t], w * __half2float(h2[(size_t)src * 16 + t]));
            atomicAdd(&accs[nl * 17 + 16], w);
        }
        __syncthreads();
    }

    int g = tid >> 4, k = tid & 15;
    bool fk = k < 10;
#pragma unroll
    for (int qq = 0; qq < 4; ++qq) {
        int nl = g * 4 + qq, nn = node0 + nl;
        if (nn >= N) continue;           // group-uniform
        float inv = 1.f / accs[nl * 17 + 16];
        float o = fk ? accs[nl * 17 + k] * inv + sb2g[k] : 0.f;
        float v = sb1[k];
#pragma unroll
        for (int kk = 0; kk < 10; ++kk) {
            float ov = __shfl(o, kk, 16);
            if (fk) v += ov * sW1[kk * 10 + k];
        }
        float t = fmaxf(v, 0.f);
        float cc = t * sW2[k];           // zero for k>=10
#pragma unroll
        for (int off = 1; off < 16; off <<= 1) cc += __shfl_xor(cc, off, 16);
        if (k == 0) out[nn] = cc + sbl2;
    }
}

extern "C" void kernel_launch(void* const* d_in, const int* in_sizes, int n_in,
                              void* d_out, int out_size, void* d_ws, size_t ws_size,
                              hipStream_t stream)
{
    const float* x   = (const float*)d_in[0];
    const int*   ei  = (const int*)  d_in[1];   // [2][E] int32
    const float* W1  = (const float*)d_in[2];
    const float* a1s = (const float*)d_in[3];
    const float* a1d = (const float*)d_in[4];
    const float* b1  = (const float*)d_in[5];
    const float* W2  = (const float*)d_in[6];
    const float* a2s = (const float*)d_in[7];
    const float* a2d = (const float*)d_in[8];
    const float* b2  = (const float*)d_in[9];
    const float* Wl1 = (const float*)d_in[10];
    const float* bl1 = (const float*)d_in[11];
    const float* Wl2 = (const float*)d_in[12];
    const float* bl2 = (const float*)d_in[13];

    int N = in_sizes[0] / 128;
    int E = in_sizes[1] / 2;
    const int* ei_src = ei;
    const int* ei_dst = ei + E;
    int NSB = (N + BNODES - 1) >> FSH;       // 782 buckets (<= NSBMAX)

    size_t Np = ((size_t)N + 3) & ~(size_t)3;
    size_t need_bytes = (16 + (size_t)NSB * 16) * 4 + Np * 20 * 4 + (size_t)NSB * CAPB * 4;
    if (ws_size < need_bytes) return;  // degrade to wrong-answer, never fault

    // layout: [gmax1 gmax2 pad..16][bcur NSB*16][h1 s1 d1 h2 s2 d2][pairs]
    unsigned* gmax1 = (unsigned*)d_ws;       // [0]
    unsigned* gmax2 = gmax1 + 1;             // [1]
    int* bcur = (int*)d_ws + 16;             // NSB*16 (1 cursor per 64B), RELATIVE
    float* rest = (float*)d_ws + 16 + (size_t)NSB * 16;
    __half* h1 = (__half*)rest;              // Np*16 halves
    float* s1 = rest + Np * 8;               // Np
    float* d1 = s1 + Np;                     // Np
    __half* h2 = (__half*)(d1 + Np);         // Np*16 halves (cols 10..15 zero)
    float* s2 = (float*)(h2) + Np * 8;       // Np
    float* d2 = s2 + Np;                     // Np
    unsigned* pairs = (unsigned*)(d2 + Np);  // NSB*CAPB

    int NG = (N + 63) / 64;
    int NC = (E + TILE - 1) / TILE;

    // zero gmax + relative bucket cursors in one memset (replaces k_init)
    hipMemsetAsync(d_ws, 0, (16 + (size_t)NSB * 16) * sizeof(int), stream);
    hipLaunchKernelGGL(k_front, dim3(NG + NC), dim3(256), 0, stream,
                       x, W1, a1s, a1d, h1, s1, d1, gmax1,
                       ei_src, ei_dst, bcur, pairs, N, E, NG, NC, NSB);
    hipLaunchKernelGGL(k_agg1, dim3(NSB), dim3(512), 0, stream,
                       bcur, pairs, ei_src, ei_dst, s1, d1, h1, b1, W2, a2s, a2d,
                       h2, s2, d2, gmax1, gmax2, N, E);
    hipLaunchKernelGGL(k_agg2, dim3(NSB), dim3(512), 0, stream,
                       bcur, pairs, ei_src, ei_dst, s2, d2, h2, b2, Wl1, bl1, Wl2, bl2,
                       gmax2, (float*)d_out, N, E);
}

// Round 4
// 280.612 us; speedup vs baseline: 1.0178x; 1.0178x over previous
//
#include <hip/hip_runtime.h>
#include <hip/hip_fp16.h>

// GAT (2 layers, heads=1) + 2-layer MLP head. N=100000, E=3200000, D=128.
// R19 = occupancy round. All kernels were grid/LDS-capped (agg: 782 blocks =
// 3/CU, 45% occ; front: 42KB LDS union = 3/CU, 18-24% occ).
//  - agg: 2 half-blocks per bucket (64 nodes, 256 thr, R11 gather verbatim).
//    Grid 1564, LDS 18.5KB -> up to 8 blocks/CU. srt per-node order is
//    unchanged -> bitwise-identical aggregation. Half-overflow -> rescan.
//  - front gemm role: no x LDS stage; per-lane j-partition (32 x floats in
//    VGPRs), bank-padded W (base q*516, conflict-free), 4-lane butterfly
//    reduce. LDS 8.2KB; union with csplit (TILE 4096) = 28.7KB -> 5 blocks/CU.
// Overflow -> full-rescan fallback keeps arbitrary inputs correct.
// Softmax stabilization uses a GLOBAL upper bound m̄_i = leaky(gmax_asrc+adst_i)
// (valid since leaky_relu is monotone); alpha is mathematically unchanged.

#define NEG 0.2f
#define FSH 7
#define BNODES 128           // nodes per bucket
#define NSBMAX 1024          // >= ceil(100000/128)=782
#define CAPB 4608            // per-bucket region capacity (mean 4096, +8 sigma)
#define TILE 4096            // edges per csplit block (256 threads, 16 iters)
#define HN 64                // nodes per agg half-block
#define SCAP 3072            // per-half srt capacity (mean 2048, +22 sigma)
#define PESA 18              // ceil(CAPB/256) register-staged pairs per thread

__device__ __forceinline__ float lrelu(float x) { return x > 0.0f ? x : NEG * x; }

__device__ __forceinline__ unsigned fenc(float f) {
    unsigned u = __float_as_uint(f);
    return (u & 0x80000000u) ? ~u : (u | 0x80000000u);
}
__device__ __forceinline__ float fdec(unsigned e) {
    return (e & 0x80000000u) ? __uint_as_float(e & 0x7FFFFFFFu) : __uint_as_float(~e);
}

// load 4 consecutive halves as float4 (8B load)
__device__ __forceinline__ float4 ldh4(const __half* h, size_t off) {
    uint2 u = *(const uint2*)(h + off);
    __half2 a = *(__half2*)&u.x, b = *(__half2*)&u.y;
    float2 fa = __half22float2(a), fb = __half22float2(b);
    return make_float4(fa.x, fa.y, fb.x, fb.y);
}

// ---- fused front-end: gemm role + csplit role in one grid ----
__global__ __launch_bounds__(256) void k_front(
    const float* __restrict__ x, const float* __restrict__ W1,
    const float* __restrict__ a1s, const float* __restrict__ a1d,
    __half* __restrict__ h1, float* __restrict__ s1, float* __restrict__ d1,
    unsigned* __restrict__ gmax,
    const int* __restrict__ esrc, const int* __restrict__ edst,
    int* __restrict__ bcur, unsigned* __restrict__ pairs,
    int N, int E, int NG, int NC, int NSB)
{
    // union LDS: csplit TILE + 3*NSBMAX + 4 = 7172 words (28.7KB)
    //            gemm: padded W 2060 + wm 4 = 2064 words (8.3KB)
    __shared__ float smem[7172];
    int tid = threadIdx.x;
    int bid = blockIdx.x;
    long long T = (long long)NG + NC;
    int before = (int)(((long long)bid * NC) / T);       // csplit blocks before bid
    int isc = (int)((((long long)bid + 1) * NC) / T) > before;

    if (isc) {
        // ------------------ csplit role ------------------
        unsigned* lsrt = (unsigned*)smem;           // TILE
        int* lhist = (int*)smem + TILE;             // NSBMAX
        int* lofs  = lhist + NSBMAX;                // NSBMAX
        int* gbase = lofs + NSBMAX;                 // NSBMAX
        int* wsum  = gbase + NSBMAX;                // 4
        int cid = before;
        int base = cid * TILE;
        int tcnt = min(TILE, E - base);
        for (int i = tid; i < NSB; i += 256) lhist[i] = 0;
        __syncthreads();
        for (int i = tid; i < tcnt; i += 256)
            atomicAdd(&lhist[edst[base + i] >> FSH], 1);
        __syncthreads();
        // 4 keys per thread scan (NSB <= 1024 = 4*256)
        int i0 = 4 * tid;
        int a0 = (i0 + 0 < NSB) ? lhist[i0 + 0] : 0;
        int a1 = (i0 + 1 < NSB) ? lhist[i0 + 1] : 0;
        int a2 = (i0 + 2 < NSB) ? lhist[i0 + 2] : 0;
        int a3 = (i0 + 3 < NSB) ? lhist[i0 + 3] : 0;
        int s = a0 + a1 + a2 + a3, pfx = s;
#pragma unroll
        for (int off = 1; off < 64; off <<= 1) {
            int t = __shfl_up(pfx, off, 64);
            if ((tid & 63) >= off) pfx += t;
        }
        if ((tid & 63) == 63) wsum[tid >> 6] = pfx;
        __syncthreads();
        int carry = 0;
        for (int w = 0; w < (tid >> 6); ++w) carry += wsum[w];
        int excl = pfx + carry - s;
        if (i0 + 0 < NSB) { lofs[i0 + 0] = excl;                 gbase[i0 + 0] = a0 ? atomicAdd(&bcur[(i0 + 0) * 16], a0) : 0; }
        if (i0 + 1 < NSB) { lofs[i0 + 1] = excl + a0;            gbase[i0 + 1] = a1 ? atomicAdd(&bcur[(i0 + 1) * 16], a1) : 0; }
        if (i0 + 2 < NSB) { lofs[i0 + 2] = excl + a0 + a1;       gbase[i0 + 2] = a2 ? atomicAdd(&bcur[(i0 + 2) * 16], a2) : 0; }
        if (i0 + 3 < NSB) { lofs[i0 + 3] = excl + a0 + a1 + a2;  gbase[i0 + 3] = a3 ? atomicAdd(&bcur[(i0 + 3) * 16], a3) : 0; }
        __syncthreads();
        if (i0 + 0 < NSB) lhist[i0 + 0] = lofs[i0 + 0];   // cursors
        if (i0 + 1 < NSB) lhist[i0 + 1] = lofs[i0 + 1];
        if (i0 + 2 < NSB) lhist[i0 + 2] = lofs[i0 + 2];
        if (i0 + 3 < NSB) lhist[i0 + 3] = lofs[i0 + 3];
        __syncthreads();
        for (int i = tid; i < tcnt; i += 256) {
            int e = base + i;
            int d = edst[e], srcv = esrc[e];
            int pos = atomicAdd(&lhist[d >> FSH], 1);
            lsrt[pos] = ((unsigned)(d & (BNODES - 1)) << 17) | (unsigned)srcv;
        }
        __syncthreads();
        // flattened flush: binary search run id, coalesced run-contiguous stores
        for (int i = tid; i < tcnt; i += 256) {
            int lo = 0, hi = NSB - 1;
            while (lo < hi) { int mid = (lo + hi + 1) >> 1; if (lofs[mid] <= i) lo = mid; else hi = mid - 1; }
            int rel = gbase[lo] + (i - lofs[lo]);
            if (rel < CAPB) pairs[(size_t)lo * CAPB + rel] = lsrt[i];
        }
        return;
    }

    // ------------------ gemm role (no x stage; j-partitioned lanes) ------------------
    float* sW = smem;                 // padded: idx i -> i + ((i>>9)<<2), max 2059
    float* wm = smem + 2060;          // 4
    int gid = bid - before;
    for (int i = tid; i < 2048; i += 256) sW[i + ((i >> 9) << 2)] = W1[i];
    int node0 = gid * 64;
    int node = node0 + (tid >> 2);
    int q = tid & 3;
    bool valid = node < N;
    // lane q owns j = q*32 .. q*32+31  (8 float4 of the node's x row)
    float4 xr[8];
    {
        const float4* xp = (const float4*)x + (size_t)node * 32 + q * 8;
#pragma unroll
        for (int k = 0; k < 8; ++k)
            xr[k] = valid ? xp[k] : make_float4(0.f, 0.f, 0.f, 0.f);
    }
    __syncthreads();

    float acc[16];
#pragma unroll
    for (int c = 0; c < 16; ++c) acc[c] = 0.f;
    int wbase = q * 516;             // q*32*16 + q*4 pad -> banks 4q.. (conflict-free)
#pragma unroll
    for (int k = 0; k < 8; ++k) {
        float xs0 = xr[k].x, xs1 = xr[k].y, xs2 = xr[k].z, xs3 = xr[k].w;
#pragma unroll
        for (int t = 0; t < 4; ++t) {
            float xv = (t == 0) ? xs0 : (t == 1) ? xs1 : (t == 2) ? xs2 : xs3;
            const float4* wrow = (const float4*)&sW[wbase + (k * 4 + t) * 16];
            float4 w0 = wrow[0], w1 = wrow[1], w2 = wrow[2], w3 = wrow[3];
            acc[0]  += xv * w0.x; acc[1]  += xv * w0.y; acc[2]  += xv * w0.z; acc[3]  += xv * w0.w;
            acc[4]  += xv * w1.x; acc[5]  += xv * w1.y; acc[6]  += xv * w1.z; acc[7]  += xv * w1.w;
            acc[8]  += xv * w2.x; acc[9]  += xv * w2.y; acc[10] += xv * w2.z; acc[11] += xv * w2.w;
            acc[12] += xv * w3.x; acc[13] += xv * w3.y; acc[14] += xv * w3.z; acc[15] += xv * w3.w;
        }
    }
    // butterfly over the 4 lanes: all lanes end with the full 16 sums
#pragma unroll
    for (int c = 0; c < 16; ++c) {
        acc[c] += __shfl_xor(acc[c], 1);
        acc[c] += __shfl_xor(acc[c], 2);
    }
    float sv = 0.f, dv = 0.f;
    {
        const float4* asp = (const float4*)a1s;
        const float4* adp = (const float4*)a1d;
#pragma unroll
        for (int r = 0; r < 4; ++r) {
            float4 as = asp[r], ad = adp[r];
            sv += acc[r*4+0]*as.x + acc[r*4+1]*as.y + acc[r*4+2]*as.z + acc[r*4+3]*as.w;
            dv += acc[r*4+0]*ad.x + acc[r*4+1]*ad.y + acc[r*4+2]*ad.z + acc[r*4+3]*ad.w;
        }
    }
    if (valid) {
        float4 av;
        if      (q == 0) av = make_float4(acc[0],  acc[1],  acc[2],  acc[3]);
        else if (q == 1) av = make_float4(acc[4],  acc[5],  acc[6],  acc[7]);
        else if (q == 2) av = make_float4(acc[8],  acc[9],  acc[10], acc[11]);
        else             av = make_float4(acc[12], acc[13], acc[14], acc[15]);
        __half2 p0 = __floats2half2_rn(av.x, av.y);
        __half2 p1 = __floats2half2_rn(av.z, av.w);
        uint2 u; u.x = *(unsigned*)&p0; u.y = *(unsigned*)&p1;
        *(uint2*)&h1[(size_t)node * 16 + q * 4] = u;
        if (q == 0) { s1[node] = sv; d1[node] = dv; }
    }
    float m = valid ? sv : -3.4e38f;
#pragma unroll
    for (int off = 32; off >= 1; off >>= 1) m = fmaxf(m, __shfl_xor(m, off));
    if ((tid & 63) == 0) wm[tid >> 6] = m;
    __syncthreads();
    if (tid == 0) {
        float b = fmaxf(fmaxf(wm[0], wm[1]), fmaxf(wm[2], wm[3]));
        atomicMax(gmax, fenc(b));
    }
}

// ---- layer-1 agg: half-bucket blocks (64 nodes, 256 thr), R11 gather ----
__global__ __launch_bounds__(256) void k_agg1(
    const int* __restrict__ bcur, const unsigned* __restrict__ pairs,
    const int* __restrict__ esrc, const int* __restrict__ edst,
    const float* __restrict__ s1, const float* __restrict__ d1, const __half* __restrict__ h1,
    const float* __restrict__ b1, const float* __restrict__ W2,
    const float* __restrict__ a2s, const float* __restrict__ a2d,
    __half* __restrict__ h2, float* __restrict__ s2, float* __restrict__ d2,
    const unsigned* __restrict__ gmax1p, unsigned* __restrict__ gmax2, int N, int E)
{
    __shared__ unsigned srt[SCAP];
    __shared__ float accs[HN * 17];
    __shared__ int lcnt[HN];
    __shared__ int lofs[HN + 1];
    __shared__ float dds[HN], mbs[HN];
    __shared__ float sW[160], sb[16], sas[16], sad[16];
    __shared__ float wm[4];

    int tid = threadIdx.x;
    int fb = blockIdx.x >> 1;            // bucket
    int hf = blockIdx.x & 1;             // half
    int node0 = blockIdx.x << 6;         // fb*128 + hf*64
    if (tid < 160) sW[tid] = W2[tid];
    if (tid < 16) {
        sb[tid]  = b1[tid];
        sas[tid] = (tid < 10) ? a2s[tid] : 0.f;
        sad[tid] = (tid < 10) ? a2d[tid] : 0.f;
    }
    float g0 = fdec(*gmax1p);
    if (tid < HN) {
        int n = node0 + tid;
        float dd = (n < N) ? d1[n] : 0.f;
        dds[tid] = dd; mbs[tid] = lrelu(g0 + dd);
        lcnt[tid] = 0;
    }
    __syncthreads();

    int rbase = fb * CAPB;
    int cnt = bcur[fb * 16];             // RELATIVE count; > CAPB means overflow
    int gg = tid >> 2, q = tid & 3;      // 64 groups x 4 lanes, 1 node each

    bool ok = (cnt <= CAPB);
    unsigned pe[PESA];
    if (ok) {
        // count pass with register staging; only this half's pairs counted
#pragma unroll
        for (int u = 0; u < PESA; ++u) {
            int i = tid + u * 256;
            bool v = (i < cnt);
            pe[u] = v ? pairs[rbase + i] : 0u;
            if (v) {
                int dl = (pe[u] >> 17) & (BNODES - 1);
                if ((dl >> 6) == hf) atomicAdd(&lcnt[dl & (HN - 1)], 1);
            }
        }
        __syncthreads();
        // 64-key scan in wave 0
        if (tid < HN) {
            int c = lcnt[tid];
            int pfx = c;
#pragma unroll
            for (int off = 1; off < 64; off <<= 1) {
                int t = __shfl_up(pfx, off, 64);
                if (tid >= off) pfx += t;
            }
            lofs[tid + 1] = pfx;
            lcnt[tid] = pfx - c;
            if (tid == 0) lofs[0] = 0;
        }
        __syncthreads();
        if (lofs[HN] > SCAP) ok = false;
    }

    if (ok) {
        // scatter pass from registers -> dst-sorted srcs (this half only)
#pragma unroll
        for (int u = 0; u < PESA; ++u) {
            int i = tid + u * 256;
            if (i < cnt) {
                unsigned p = pe[u];
                int dl = (p >> 17) & (BNODES - 1);
                if ((dl >> 6) == hf) {
                    int pos = atomicAdd(&lcnt[dl & (HN - 1)], 1);
                    srt[pos] = p & 0x1FFFF;
                }
            }
        }
        __syncthreads();

        // self-loop init + register gather (1 exp/edge via width-4 shfl)
        int n = node0 + gg;
        float4 accv; float den;
        if (n < N) {
            float w = __expf(lrelu(s1[n] + dds[gg]) - mbs[gg]);
            float4 hv = ldh4(h1, (size_t)n * 16 + 4 * q);
            accv = make_float4(w * hv.x, w * hv.y, w * hv.z, w * hv.w);
            den = w;
        } else { accv = make_float4(0.f, 0.f, 0.f, 0.f); den = 0.f; }
        {
            float dd = dds[gg], mb = mbs[gg];
            int j = lofs[gg], j1 = lofs[gg + 1];
            for (; j + 4 <= j1; j += 4) {
                int e0 = srt[j], e1 = srt[j + 1], e2 = srt[j + 2], e3 = srt[j + 3];
                float4 H0 = ldh4(h1, (size_t)e0 * 16 + 4 * q);
                float4 H1 = ldh4(h1, (size_t)e1 * 16 + 4 * q);
                float4 H2 = ldh4(h1, (size_t)e2 * 16 + 4 * q);
                float4 H3 = ldh4(h1, (size_t)e3 * 16 + 4 * q);
                int eq = srt[j + q];
                float wq = __expf(lrelu(s1[eq] + dd) - mb);
                float w0 = __shfl(wq, 0, 4), w1 = __shfl(wq, 1, 4);
                float w2 = __shfl(wq, 2, 4), w3 = __shfl(wq, 3, 4);
                accv.x += w0 * H0.x + w1 * H1.x + w2 * H2.x + w3 * H3.x;
                accv.y += w0 * H0.y + w1 * H1.y + w2 * H2.y + w3 * H3.y;
                accv.z += w0 * H0.z + w1 * H1.z + w2 * H2.z + w3 * H3.z;
                accv.w += w0 * H0.w + w1 * H1.w + w2 * H2.w + w3 * H3.w;
                den += (w0 + w1) + (w2 + w3);
            }
            for (; j < j1; ++j) {
                int e0 = srt[j];
                float w0 = __expf(lrelu(s1[e0] + dd) - mb);
                float4 H0 = ldh4(h1, (size_t)e0 * 16 + 4 * q);
                accv.x += w0 * H0.x; accv.y += w0 * H0.y;
                accv.z += w0 * H0.z; accv.w += w0 * H0.w;
                den += w0;
            }
        }
        accs[gg * 17 + 4 * q + 0] = accv.x;
        accs[gg * 17 + 4 * q + 1] = accv.y;
        accs[gg * 17 + 4 * q + 2] = accv.z;
        accs[gg * 17 + 4 * q + 3] = accv.w;
        if (q == 0) accs[gg * 17 + 16] = den;
        __syncthreads();
    } else {
        // overflow: rescan source edges for this 64-node window (never-path)
        for (int i = tid; i < HN * 17; i += 256) accs[i] = 0.f;
        __syncthreads();
        if (tid < HN) {
            int n = node0 + tid;
            if (n < N) {
                float w = __expf(lrelu(s1[n] + dds[tid]) - mbs[tid]);
#pragma unroll
                for (int t = 0; t < 16; ++t)
                    accs[tid * 17 + t] = w * __half2float(h1[(size_t)n * 16 + t]);
                accs[tid * 17 + 16] = w;
            }
        }
        __syncthreads();
        for (int i = tid; i < E; i += 256) {
            int d = edst[i];
            if ((d >> 6) != blockIdx.x) continue;
            int nl = d & (HN - 1), src = esrc[i];
            float w = __expf(lrelu(s1[src] + dds[nl]) - mbs[nl]);
#pragma unroll
            for (int t = 0; t < 16; ++t)
                atomicAdd(&accs[nl * 17 + t], w * __half2float(h1[(size_t)src * 16 + t]));
            atomicAdd(&accs[nl * 17 + 16], w);
        }
        __syncthreads();
    }

    // epilogue: 16 groups of 16 lanes, 4 nodes each (64 nodes)
    int g = tid >> 4, k = tid & 15;
    float sval = -3.4e38f;
#pragma unroll
    for (int qq = 0; qq < 4; ++qq) {
        int nl = g * 4 + qq, nn = node0 + nl;
        if (nn >= N) continue;           // group-uniform
        float inv = 1.f / accs[nl * 17 + 16];
        float o = fmaxf(accs[nl * 17 + k] * inv + sb[k], 0.f);
        float hh = 0.f;
#pragma unroll
        for (int kk = 0; kk < 16; ++kk) {
            float ov = __shfl(o, kk, 16);
            if (k < 10) hh += ov * sW[kk * 10 + k];
        }
        if (k >= 10) hh = 0.f;
        float ts = hh * sas[k];
        float td = hh * sad[k];
#pragma unroll
        for (int off = 1; off < 16; off <<= 1) {
            ts += __shfl_xor(ts, off, 16);
            td += __shfl_xor(td, off, 16);
        }
        h2[(size_t)nn * 16 + k] = __float2half_rn(hh);  // zero-padded cols 10..15
        if (k == 0) { s2[nn] = ts; d2[nn] = td; }
        sval = fmaxf(sval, ts);
    }
    float m = sval;
#pragma unroll
    for (int off = 32; off >= 1; off >>= 1) m = fmaxf(m, __shfl_xor(m, off));
    if ((tid & 63) == 0) wm[tid >> 6] = m;
    __syncthreads();
    if (tid == 0) {
        float bmx = fmaxf(fmaxf(wm[0], wm[1]), fmaxf(wm[2], wm[3]));
        atomicMax(gmax2, fenc(bmx));
    }
}

// ---- layer-2 agg (same structure) + norm/bias + MLP head -> out ----
__global__ __launch_bounds__(256) void k_agg2(
    const int* __restrict__ bcur, const unsigned* __restrict__ pairs,
    const int* __restrict__ esrc, const int* __restrict__ edst,
    const float* __restrict__ s2, const float* __restrict__ d2, const __half* __restrict__ h2,
    const float* __restrict__ b2, const float* __restrict__ Wl1, const float* __restrict__ bl1,
    const float* __restrict__ Wl2, const float* __restrict__ bl2,
    const unsigned* __restrict__ gmax2p, float* __restrict__ out, int N, int E)
{
    __shared__ unsigned srt[SCAP];
    __shared__ float accs[HN * 17];
    __shared__ int lcnt[HN];
    __shared__ int lofs[HN + 1];
    __shared__ float dds[HN], mbs[HN];
    __shared__ float sW1[100], sb1[16], sW2[16], sb2g[16];
    __shared__ float sbl2;

    int tid = threadIdx.x;
    int fb = blockIdx.x >> 1;
    int hf = blockIdx.x & 1;
    int node0 = blockIdx.x << 6;
    if (tid < 100) sW1[tid] = Wl1[tid];
    if (tid < 16) {
        sb1[tid]  = (tid < 10) ? bl1[tid] : 0.f;
        sW2[tid]  = (tid < 10) ? Wl2[tid] : 0.f;
        sb2g[tid] = (tid < 10) ? b2[tid]  : 0.f;
    }
    if (tid == 0) sbl2 = bl2[0];
    float g0 = fdec(*gmax2p);
    if (tid < HN) {
        int n = node0 + tid;
        float dd = (n < N) ? d2[n] : 0.f;
        dds[tid] = dd; mbs[tid] = lrelu(g0 + dd);
        lcnt[tid] = 0;
    }
    __syncthreads();

    int rbase = fb * CAPB;
    int cnt = bcur[fb * 16];
    int gg = tid >> 2, q = tid & 3;

    bool ok = (cnt <= CAPB);
    unsigned pe[PESA];
    if (ok) {
#pragma unroll
        for (int u = 0; u < PESA; ++u) {
            int i = tid + u * 256;
            bool v = (i < cnt);
            pe[u] = v ? pairs[rbase + i] : 0u;
            if (v) {
                int dl = (pe[u] >> 17) & (BNODES - 1);
                if ((dl >> 6) == hf) atomicAdd(&lcnt[dl & (HN - 1)], 1);
            }
        }
        __syncthreads();
        if (tid < HN) {
            int c = lcnt[tid];
            int pfx = c;
#pragma unroll
            for (int off = 1; off < 64; off <<= 1) {
                int t = __shfl_up(pfx, off, 64);
                if (tid >= off) pfx += t;
            }
            lofs[tid + 1] = pfx;
            lcnt[tid] = pfx - c;
            if (tid == 0) lofs[0] = 0;
        }
        __syncthreads();
        if (lofs[HN] > SCAP) ok = false;
    }

    if (ok) {
#pragma unroll
        for (int u = 0; u < PESA; ++u) {
            int i = tid + u * 256;
            if (i < cnt) {
                unsigned p = pe[u];
                int dl = (p >> 17) & (BNODES - 1);
                if ((dl >> 6) == hf) {
                    int pos = atomicAdd(&lcnt[dl & (HN - 1)], 1);
                    srt[pos] = p & 0x1FFFF;
                }
            }
        }
        __syncthreads();

        int n = node0 + gg;
        float4 accv; float den;
        if (n < N) {
            float w = __expf(lrelu(s2[n] + dds[gg]) - mbs[gg]);
            float4 hv = ldh4(h2, (size_t)n * 16 + 4 * q);   // zero-padded
            accv = make_float4(w * hv.x, w * hv.y, w * hv.z, w * hv.w);
            den = w;
        } else { accv = make_float4(0.f, 0.f, 0.f, 0.f); den = 0.f; }
        {
            float dd = dds[gg], mb = mbs[gg];
            int j = lofs[gg], j1 = lofs[gg + 1];
            for (; j + 4 <= j1; j += 4) {
                int e0 = srt[j], e1 = srt[j + 1], e2 = srt[j + 2], e3 = srt[j + 3];
                float4 H0 = ldh4(h2, (size_t)e0 * 16 + 4 * q);
                float4 H1 = ldh4(h2, (size_t)e1 * 16 + 4 * q);
                float4 H2 = ldh4(h2, (size_t)e2 * 16 + 4 * q);
                float4 H3 = ldh4(h2, (size_t)e3 * 16 + 4 * q);
                int eq = srt[j + q];
                float wq = __expf(lrelu(s2[eq] + dd) - mb);
                float w0 = __shfl(wq, 0, 4), w1 = __shfl(wq, 1, 4);
                float w2 = __shfl(wq, 2, 4), w3 = __shfl(wq, 3, 4);
                accv.x += w0 * H0.x + w1 * H1.x + w2 * H2.x + w3 * H3.x;
                accv.y += w0 * H0.y + w1 * H1.y + w2 * H2.y + w3 * H3.y;
                accv.z += w0 * H0.z + w1 * H1.z + w2 * H2.z + w3 * H3.z;
                accv.w += w0 * H0.w + w1 * H1.w + w2 * H2.w + w3 * H3.w;
                den += (w0 + w1) + (w2 + w3);
            }
            for (; j < j1; ++j) {
                int e0 = srt[j];
                float w0 = __expf(lrelu(s2[e0] + dd) - mb);
                float4 H0 = ldh4(h2, (size_t)e0 * 16 + 4 * q);
                accv.x += w0 * H0.x; accv.y += w0 * H0.y;
                accv.z += w0 * H0.z; accv.w += w0 * H0.w;
                den += w0;
            }
        }
        accs[gg * 17 + 4 * q + 0] = accv.x;
        accs[gg * 17 + 4 * q + 1] = accv.y;
        accs[gg * 17 + 4 * q + 2] = accv.z;
        accs[gg * 17 + 4 * q + 3] = accv.w;
        if (q == 0) accs[gg * 17 + 16] = den;
        __syncthreads();
    } else {
        for (int i = tid; i < HN * 17; i += 256) accs[i] = 0.f;
        __syncthreads();
        if (tid < HN) {
            int n = node0 + tid;
            if (n < N) {
                float w = __expf(lrelu(s2[n] + dds[tid]) - mbs[tid]);
#pragma unroll
                for (int t = 0; t < 16; ++t)
                    accs[tid * 17 + t] = w * __half2float(h2[(size_t)n * 16 + t]);
                accs[tid * 17 + 16] = w;
            }
        }
        __syncthreads();
        for (int i = tid; i < E; i += 256) {
            int d = edst[i];
            if ((d >> 6) != blockIdx.x) continue;
            int nl = d & (HN - 1), src = esrc[i];
            float w = __expf(lrelu(s2[src] + dds[nl]) - mbs[nl]);
#pragma unroll
            for (int t = 0; t < 16; ++t)
                atomicAdd(&accs[nl * 17 + t], w * __half2float(h2[(size_t)src * 16 + t]));
            atomicAdd(&accs[nl * 17 + 16], w);
        }
        __syncthreads();
    }

    int g = tid >> 4, k = tid & 15;
    bool fk = k < 10;
#pragma unroll
    for (int qq = 0; qq < 4; ++qq) {
        int nl = g * 4 + qq, nn = node0 + nl;
        if (nn >= N) continue;           // group-uniform
        float inv = 1.f / accs[nl * 17 + 16];
        float o = fk ? accs[nl * 17 + k] * inv + sb2g[k] : 0.f;
        float v = sb1[k];
#pragma unroll
        for (int kk = 0; kk < 10; ++kk) {
            float ov = __shfl(o, kk, 16);
            if (fk) v += ov * sW1[kk * 10 + k];
        }
        float t = fmaxf(v, 0.f);
        float cc = t * sW2[k];           // zero for k>=10
#pragma unroll
        for (int off = 1; off < 16; off <<= 1) cc += __shfl_xor(cc, off, 16);
        if (k == 0) out[nn] = cc + sbl2;
    }
}

extern "C" void kernel_launch(void* const* d_in, const int* in_sizes, int n_in,
                              void* d_out, int out_size, void* d_ws, size_t ws_size,
                              hipStream_t stream)
{
    const float* x   = (const float*)d_in[0];
    const int*   ei  = (const int*)  d_in[1];   // [2][E] int32
    const float* W1  = (const float*)d_in[2];
    const float* a1s = (const float*)d_in[3];
    const float* a1d = (const float*)d_in[4];
    const float* b1  = (const float*)d_in[5];
    const float* W2  = (const float*)d_in[6];
    const float* a2s = (const float*)d_in[7];
    const float* a2d = (const float*)d_in[8];
    const float* b2  = (const float*)d_in[9];
    const float* Wl1 = (const float*)d_in[10];
    const float* bl1 = (const float*)d_in[11];
    const float* Wl2 = (const float*)d_in[12];
    const float* bl2 = (const float*)d_in[13];

    int N = in_sizes[0] / 128;
    int E = in_sizes[1] / 2;
    const int* ei_src = ei;
    const int* ei_dst = ei + E;
    int NSB = (N + BNODES - 1) >> FSH;       // 782 buckets (<= NSBMAX)

    size_t Np = ((size_t)N + 3) & ~(size_t)3;
    size_t need_bytes = (16 + (size_t)NSB * 16) * 4 + Np * 20 * 4 + (size_t)NSB * CAPB * 4;
    if (ws_size < need_bytes) return;  // degrade to wrong-answer, never fault

    // layout: [gmax1 gmax2 pad..16][bcur NSB*16][h1 s1 d1 h2 s2 d2][pairs]
    unsigned* gmax1 = (unsigned*)d_ws;       // [0]
    unsigned* gmax2 = gmax1 + 1;             // [1]
    int* bcur = (int*)d_ws + 16;             // NSB*16 (1 cursor per 64B), RELATIVE
    float* rest = (float*)d_ws + 16 + (size_t)NSB * 16;
    __half* h1 = (__half*)rest;              // Np*16 halves
    float* s1 = rest + Np * 8;               // Np
    float* d1 = s1 + Np;                     // Np
    __half* h2 = (__half*)(d1 + Np);         // Np*16 halves (cols 10..15 zero)
    float* s2 = (float*)(h2) + Np * 8;       // Np
    float* d2 = s2 + Np;                     // Np
    unsigned* pairs = (unsigned*)(d2 + Np);  // NSB*CAPB

    int NG = (N + 63) / 64;
    int NC = (E + TILE - 1) / TILE;

    // zero gmax + relative bucket cursors in one memset (replaces k_init)
    hipMemsetAsync(d_ws, 0, (16 + (size_t)NSB * 16) * sizeof(int), stream);
    hipLaunchKernelGGL(k_front, dim3(NG + NC), dim3(256), 0, stream,
                       x, W1, a1s, a1d, h1, s1, d1, gmax1,
                       ei_src, ei_dst, bcur, pairs, N, E, NG, NC, NSB);
    hipLaunchKernelGGL(k_agg1, dim3(NSB * 2), dim3(256), 0, stream,
                       bcur, pairs, ei_src, ei_dst, s1, d1, h1, b1, W2, a2s, a2d,
                       h2, s2, d2, gmax1, gmax2, N, E);
    hipLaunchKernelGGL(k_agg2, dim3(NSB * 2), dim3(256), 0, stream,
                       bcur, pairs, ei_src, ei_dst, s2, d2, h2, b2, Wl1, bl1, Wl2, bl2,
                       gmax2, (float*)d_out, N, E);
}

// Round 5
// 276.544 us; speedup vs baseline: 1.0328x; 1.0147x over previous
//
#include <hip/hip_runtime.h>
#include <hip/hip_fp16.h>

// GAT (2 layers, heads=1) + 2-layer MLP head. N=100000, E=3200000, D=128.
// R20 = R19 + csplit flush de-serialization. The flush's run-id binary
// search (10 serially-dependent LDS reads/edge, unhideable latency chain)
// is replaced by a ushort rid[TILE] recorded during the scatter pass
// (bucket id is already in hand there); flush iterations become fully
// independent -> pipelineable. edst is register-staged across hist+scatter
// (kills the second 12.8MB read). LDS 36.9KB -> 4 blocks/CU.
// agg kernels: R19 half-bucket blocks. Overflow -> full-rescan fallback.
// Softmax stabilization uses a GLOBAL upper bound m̄_i = leaky(gmax_asrc+adst_i)
// (valid since leaky_relu is monotone); alpha is mathematically unchanged.

#define NEG 0.2f
#define FSH 7
#define BNODES 128           // nodes per bucket
#define NSBMAX 1024          // >= ceil(100000/128)=782
#define CAPB 4608            // per-bucket region capacity (mean 4096, +8 sigma)
#define TILE 4096            // edges per csplit block (256 threads, 16/thread)
#define EPT 16               // TILE/256 register-staged edges per thread
#define HN 64                // nodes per agg half-block
#define SCAP 3072            // per-half srt capacity (mean 2048, +22 sigma)
#define PESA 18              // ceil(CAPB/256) register-staged pairs per thread

__device__ __forceinline__ float lrelu(float x) { return x > 0.0f ? x : NEG * x; }

__device__ __forceinline__ unsigned fenc(float f) {
    unsigned u = __float_as_uint(f);
    return (u & 0x80000000u) ? ~u : (u | 0x80000000u);
}
__device__ __forceinline__ float fdec(unsigned e) {
    return (e & 0x80000000u) ? __uint_as_float(e & 0x7FFFFFFFu) : __uint_as_float(~e);
}

// load 4 consecutive halves as float4 (8B load)
__device__ __forceinline__ float4 ldh4(const __half* h, size_t off) {
    uint2 u = *(const uint2*)(h + off);
    __half2 a = *(__half2*)&u.x, b = *(__half2*)&u.y;
    float2 fa = __half22float2(a), fb = __half22float2(b);
    return make_float4(fa.x, fa.y, fb.x, fb.y);
}

// ---- fused front-end: gemm role + csplit role in one grid ----
__global__ __launch_bounds__(256) void k_front(
    const float* __restrict__ x, const float* __restrict__ W1,
    const float* __restrict__ a1s, const float* __restrict__ a1d,
    __half* __restrict__ h1, float* __restrict__ s1, float* __restrict__ d1,
    unsigned* __restrict__ gmax,
    const int* __restrict__ esrc, const int* __restrict__ edst,
    int* __restrict__ bcur, unsigned* __restrict__ pairs,
    int N, int E, int NG, int NC, int NSB)
{
    // union LDS: csplit lsrt 4096 + hist/ofs/base 3*1024 + wsum 4 + rid 2048
    //            = 9220 words (36.9KB); gemm: padded W 2060 + wm 4 (8.3KB)
    __shared__ float smem[9220];
    int tid = threadIdx.x;
    int bid = blockIdx.x;
    long long T = (long long)NG + NC;
    int before = (int)(((long long)bid * NC) / T);       // csplit blocks before bid
    int isc = (int)((((long long)bid + 1) * NC) / T) > before;

    if (isc) {
        // ------------------ csplit role ------------------
        unsigned* lsrt = (unsigned*)smem;                   // TILE
        int* lhist = (int*)smem + TILE;                     // 1024
        int* lofs  = lhist + NSBMAX;                        // 1024
        int* gbase = lofs + NSBMAX;                         // 1024
        int* wsum  = gbase + NSBMAX;                        // 4
        unsigned short* rid = (unsigned short*)(smem + TILE + 3 * NSBMAX + 4); // TILE ushorts
        int cid = before;
        int base = cid * TILE;
        int tcnt = min(TILE, E - base);
        for (int i = tid; i < NSB; i += 256) lhist[i] = 0;
        __syncthreads();
        // hist pass with register-staged dst
        int ed[EPT];
#pragma unroll
        for (int u = 0; u < EPT; ++u) {
            int i = tid + u * 256;
            ed[u] = (i < tcnt) ? edst[base + i] : -1;
            if (ed[u] >= 0) atomicAdd(&lhist[ed[u] >> FSH], 1);
        }
        __syncthreads();
        // 4 keys per thread scan (NSB <= 1024 = 4*256)
        int i0 = 4 * tid;
        int a0 = (i0 + 0 < NSB) ? lhist[i0 + 0] : 0;
        int a1 = (i0 + 1 < NSB) ? lhist[i0 + 1] : 0;
        int a2 = (i0 + 2 < NSB) ? lhist[i0 + 2] : 0;
        int a3 = (i0 + 3 < NSB) ? lhist[i0 + 3] : 0;
        int s = a0 + a1 + a2 + a3, pfx = s;
#pragma unroll
        for (int off = 1; off < 64; off <<= 1) {
            int t = __shfl_up(pfx, off, 64);
            if ((tid & 63) >= off) pfx += t;
        }
        if ((tid & 63) == 63) wsum[tid >> 6] = pfx;
        __syncthreads();
        int carry = 0;
        for (int w = 0; w < (tid >> 6); ++w) carry += wsum[w];
        int excl = pfx + carry - s;
        if (i0 + 0 < NSB) { lofs[i0 + 0] = excl;                 gbase[i0 + 0] = a0 ? atomicAdd(&bcur[(i0 + 0) * 16], a0) : 0; }
        if (i0 + 1 < NSB) { lofs[i0 + 1] = excl + a0;            gbase[i0 + 1] = a1 ? atomicAdd(&bcur[(i0 + 1) * 16], a1) : 0; }
        if (i0 + 2 < NSB) { lofs[i0 + 2] = excl + a0 + a1;       gbase[i0 + 2] = a2 ? atomicAdd(&bcur[(i0 + 2) * 16], a2) : 0; }
        if (i0 + 3 < NSB) { lofs[i0 + 3] = excl + a0 + a1 + a2;  gbase[i0 + 3] = a3 ? atomicAdd(&bcur[(i0 + 3) * 16], a3) : 0; }
        __syncthreads();
        if (i0 + 0 < NSB) lhist[i0 + 0] = lofs[i0 + 0];   // cursors
        if (i0 + 1 < NSB) lhist[i0 + 1] = lofs[i0 + 1];
        if (i0 + 2 < NSB) lhist[i0 + 2] = lofs[i0 + 2];
        if (i0 + 3 < NSB) lhist[i0 + 3] = lofs[i0 + 3];
        __syncthreads();
        // scatter pass: LDS sort + record run id (kills flush binary search)
#pragma unroll
        for (int u = 0; u < EPT; ++u) {
            int i = tid + u * 256;
            if (ed[u] >= 0) {
                int d = ed[u], srcv = esrc[base + i];
                int b = d >> FSH;
                int pos = atomicAdd(&lhist[b], 1);
                lsrt[pos] = ((unsigned)(d & (BNODES - 1)) << 17) | (unsigned)srcv;
                rid[pos] = (unsigned short)b;
            }
        }
        __syncthreads();
        // flush: independent iterations, coalesced run-contiguous stores
        for (int i = tid; i < tcnt; i += 256) {
            int r = rid[i];
            int rel = gbase[r] + (i - lofs[r]);
            if (rel < CAPB) pairs[(size_t)r * CAPB + rel] = lsrt[i];
        }
        return;
    }

    // ------------------ gemm role (no x stage; j-partitioned lanes) ------------------
    float* sW = smem;                 // padded: idx i -> i + ((i>>9)<<2), max 2059
    float* wm = smem + 2060;          // 4
    int gid = bid - before;
    for (int i = tid; i < 2048; i += 256) sW[i + ((i >> 9) << 2)] = W1[i];
    int node0 = gid * 64;
    int node = node0 + (tid >> 2);
    int q = tid & 3;
    bool valid = node < N;
    // lane q owns j = q*32 .. q*32+31  (8 float4 of the node's x row)
    float4 xr[8];
    {
        const float4* xp = (const float4*)x + (size_t)node * 32 + q * 8;
#pragma unroll
        for (int k = 0; k < 8; ++k)
            xr[k] = valid ? xp[k] : make_float4(0.f, 0.f, 0.f, 0.f);
    }
    __syncthreads();

    float acc[16];
#pragma unroll
    for (int c = 0; c < 16; ++c) acc[c] = 0.f;
    int wbase = q * 516;             // q*32*16 + q*4 pad -> banks 4q.. (conflict-free)
#pragma unroll
    for (int k = 0; k < 8; ++k) {
        float xs0 = xr[k].x, xs1 = xr[k].y, xs2 = xr[k].z, xs3 = xr[k].w;
#pragma unroll
        for (int t = 0; t < 4; ++t) {
            float xv = (t == 0) ? xs0 : (t == 1) ? xs1 : (t == 2) ? xs2 : xs3;
            const float4* wrow = (const float4*)&sW[wbase + (k * 4 + t) * 16];
            float4 w0 = wrow[0], w1 = wrow[1], w2 = wrow[2], w3 = wrow[3];
            acc[0]  += xv * w0.x; acc[1]  += xv * w0.y; acc[2]  += xv * w0.z; acc[3]  += xv * w0.w;
            acc[4]  += xv * w1.x; acc[5]  += xv * w1.y; acc[6]  += xv * w1.z; acc[7]  += xv * w1.w;
            acc[8]  += xv * w2.x; acc[9]  += xv * w2.y; acc[10] += xv * w2.z; acc[11] += xv * w2.w;
            acc[12] += xv * w3.x; acc[13] += xv * w3.y; acc[14] += xv * w3.z; acc[15] += xv * w3.w;
        }
    }
    // butterfly over the 4 lanes: all lanes end with the full 16 sums
#pragma unroll
    for (int c = 0; c < 16; ++c) {
        acc[c] += __shfl_xor(acc[c], 1);
        acc[c] += __shfl_xor(acc[c], 2);
    }
    float sv = 0.f, dv = 0.f;
    {
        const float4* asp = (const float4*)a1s;
        const float4* adp = (const float4*)a1d;
#pragma unroll
        for (int r = 0; r < 4; ++r) {
            float4 as = asp[r], ad = adp[r];
            sv += acc[r*4+0]*as.x + acc[r*4+1]*as.y + acc[r*4+2]*as.z + acc[r*4+3]*as.w;
            dv += acc[r*4+0]*ad.x + acc[r*4+1]*ad.y + acc[r*4+2]*ad.z + acc[r*4+3]*ad.w;
        }
    }
    if (valid) {
        float4 av;
        if      (q == 0) av = make_float4(acc[0],  acc[1],  acc[2],  acc[3]);
        else if (q == 1) av = make_float4(acc[4],  acc[5],  acc[6],  acc[7]);
        else if (q == 2) av = make_float4(acc[8],  acc[9],  acc[10], acc[11]);
        else             av = make_float4(acc[12], acc[13], acc[14], acc[15]);
        __half2 p0 = __floats2half2_rn(av.x, av.y);
        __half2 p1 = __floats2half2_rn(av.z, av.w);
        uint2 u; u.x = *(unsigned*)&p0; u.y = *(unsigned*)&p1;
        *(uint2*)&h1[(size_t)node * 16 + q * 4] = u;
        if (q == 0) { s1[node] = sv; d1[node] = dv; }
    }
    float m = valid ? sv : -3.4e38f;
#pragma unroll
    for (int off = 32; off >= 1; off >>= 1) m = fmaxf(m, __shfl_xor(m, off));
    if ((tid & 63) == 0) wm[tid >> 6] = m;
    __syncthreads();
    if (tid == 0) {
        float b = fmaxf(fmaxf(wm[0], wm[1]), fmaxf(wm[2], wm[3]));
        atomicMax(gmax, fenc(b));
    }
}

// ---- layer-1 agg: half-bucket blocks (64 nodes, 256 thr), R11 gather ----
__global__ __launch_bounds__(256) void k_agg1(
    const int* __restrict__ bcur, const unsigned* __restrict__ pairs,
    const int* __restrict__ esrc, const int* __restrict__ edst,
    const float* __restrict__ s1, const float* __restrict__ d1, const __half* __restrict__ h1,
    const float* __restrict__ b1, const float* __restrict__ W2,
    const float* __restrict__ a2s, const float* __restrict__ a2d,
    __half* __restrict__ h2, float* __restrict__ s2, float* __restrict__ d2,
    const unsigned* __restrict__ gmax1p, unsigned* __restrict__ gmax2, int N, int E)
{
    __shared__ unsigned srt[SCAP];
    __shared__ float accs[HN * 17];
    __shared__ int lcnt[HN];
    __shared__ int lofs[HN + 1];
    __shared__ float dds[HN], mbs[HN];
    __shared__ float sW[160], sb[16], sas[16], sad[16];
    __shared__ float wm[4];

    int tid = threadIdx.x;
    int fb = blockIdx.x >> 1;            // bucket
    int hf = blockIdx.x & 1;             // half
    int node0 = blockIdx.x << 6;         // fb*128 + hf*64
    if (tid < 160) sW[tid] = W2[tid];
    if (tid < 16) {
        sb[tid]  = b1[tid];
        sas[tid] = (tid < 10) ? a2s[tid] : 0.f;
        sad[tid] = (tid < 10) ? a2d[tid] : 0.f;
    }
    float g0 = fdec(*gmax1p);
    if (tid < HN) {
        int n = node0 + tid;
        float dd = (n < N) ? d1[n] : 0.f;
        dds[tid] = dd; mbs[tid] = lrelu(g0 + dd);
        lcnt[tid] = 0;
    }
    __syncthreads();

    int rbase = fb * CAPB;
    int cnt = bcur[fb * 16];             // RELATIVE count; > CAPB means overflow
    int gg = tid >> 2, q = tid & 3;      // 64 groups x 4 lanes, 1 node each

    bool ok = (cnt <= CAPB);
    unsigned pe[PESA];
    if (ok) {
        // count pass with register staging; only this half's pairs counted
#pragma unroll
        for (int u = 0; u < PESA; ++u) {
            int i = tid + u * 256;
            bool v = (i < cnt);
            pe[u] = v ? pairs[rbase + i] : 0u;
            if (v) {
                int dl = (pe[u] >> 17) & (BNODES - 1);
                if ((dl >> 6) == hf) atomicAdd(&lcnt[dl & (HN - 1)], 1);
            }
        }
        __syncthreads();
        // 64-key scan in wave 0
        if (tid < HN) {
            int c = lcnt[tid];
            int pfx = c;
#pragma unroll
            for (int off = 1; off < 64; off <<= 1) {
                int t = __shfl_up(pfx, off, 64);
                if (tid >= off) pfx += t;
            }
            lofs[tid + 1] = pfx;
            lcnt[tid] = pfx - c;
            if (tid == 0) lofs[0] = 0;
        }
        __syncthreads();
        if (lofs[HN] > SCAP) ok = false;
    }

    if (ok) {
        // scatter pass from registers -> dst-sorted srcs (this half only)
#pragma unroll
        for (int u = 0; u < PESA; ++u) {
            int i = tid + u * 256;
            if (i < cnt) {
                unsigned p = pe[u];
                int dl = (p >> 17) & (BNODES - 1);
                if ((dl >> 6) == hf) {
                    int pos = atomicAdd(&lcnt[dl & (HN - 1)], 1);
                    srt[pos] = p & 0x1FFFF;
                }
            }
        }
        __syncthreads();

        // self-loop init + register gather (1 exp/edge via width-4 shfl)
        int n = node0 + gg;
        float4 accv; float den;
        if (n < N) {
            float w = __expf(lrelu(s1[n] + dds[gg]) - mbs[gg]);
            float4 hv = ldh4(h1, (size_t)n * 16 + 4 * q);
            accv = make_float4(w * hv.x, w * hv.y, w * hv.z, w * hv.w);
            den = w;
        } else { accv = make_float4(0.f, 0.f, 0.f, 0.f); den = 0.f; }
        {
            float dd = dds[gg], mb = mbs[gg];
            int j = lofs[gg], j1 = lofs[gg + 1];
            for (; j + 4 <= j1; j += 4) {
                int e0 = srt[j], e1 = srt[j + 1], e2 = srt[j + 2], e3 = srt[j + 3];
                float4 H0 = ldh4(h1, (size_t)e0 * 16 + 4 * q);
                float4 H1 = ldh4(h1, (size_t)e1 * 16 + 4 * q);
                float4 H2 = ldh4(h1, (size_t)e2 * 16 + 4 * q);
                float4 H3 = ldh4(h1, (size_t)e3 * 16 + 4 * q);
                int eq = srt[j + q];
                float wq = __expf(lrelu(s1[eq] + dd) - mb);
                float w0 = __shfl(wq, 0, 4), w1 = __shfl(wq, 1, 4);
                float w2 = __shfl(wq, 2, 4), w3 = __shfl(wq, 3, 4);
                accv.x += w0 * H0.x + w1 * H1.x + w2 * H2.x + w3 * H3.x;
                accv.y += w0 * H0.y + w1 * H1.y + w2 * H2.y + w3 * H3.y;
                accv.z += w0 * H0.z + w1 * H1.z + w2 * H2.z + w3 * H3.z;
                accv.w += w0 * H0.w + w1 * H1.w + w2 * H2.w + w3 * H3.w;
                den += (w0 + w1) + (w2 + w3);
            }
            for (; j < j1; ++j) {
                int e0 = srt[j];
                float w0 = __expf(lrelu(s1[e0] + dd) - mb);
                float4 H0 = ldh4(h1, (size_t)e0 * 16 + 4 * q);
                accv.x += w0 * H0.x; accv.y += w0 * H0.y;
                accv.z += w0 * H0.z; accv.w += w0 * H0.w;
                den += w0;
            }
        }
        accs[gg * 17 + 4 * q + 0] = accv.x;
        accs[gg * 17 + 4 * q + 1] = accv.y;
        accs[gg * 17 + 4 * q + 2] = accv.z;
        accs[gg * 17 + 4 * q + 3] = accv.w;
        if (q == 0) accs[gg * 17 + 16] = den;
        __syncthreads();
    } else {
        // overflow: rescan source edges for this 64-node window (never-path)
        for (int i = tid; i < HN * 17; i += 256) accs[i] = 0.f;
        __syncthreads();
        if (tid < HN) {
            int n = node0 + tid;
            if (n < N) {
                float w = __expf(lrelu(s1[n] + dds[tid]) - mbs[tid]);
#pragma unroll
                for (int t = 0; t < 16; ++t)
                    accs[tid * 17 + t] = w * __half2float(h1[(size_t)n * 16 + t]);
                accs[tid * 17 + 16] = w;
            }
        }
        __syncthreads();
        for (int i = tid; i < E; i += 256) {
            int d = edst[i];
            if ((d >> 6) != blockIdx.x) continue;
            int nl = d & (HN - 1), src = esrc[i];
            float w = __expf(lrelu(s1[src] + dds[nl]) - mbs[nl]);
#pragma unroll
            for (int t = 0; t < 16; ++t)
                atomicAdd(&accs[nl * 17 + t], w * __half2float(h1[(size_t)src * 16 + t]));
            atomicAdd(&accs[nl * 17 + 16], w);
        }
        __syncthreads();
    }

    // epilogue: 16 groups of 16 lanes, 4 nodes each (64 nodes)
    int g = tid >> 4, k = tid & 15;
    float sval = -3.4e38f;
#pragma unroll
    for (int qq = 0; qq < 4; ++qq) {
        int nl = g * 4 + qq, nn = node0 + nl;
        if (nn >= N) continue;           // group-uniform
        float inv = 1.f / accs[nl * 17 + 16];
        float o = fmaxf(accs[nl * 17 + k] * inv + sb[k], 0.f);
        float hh = 0.f;
#pragma unroll
        for (int kk = 0; kk < 16; ++kk) {
            float ov = __shfl(o, kk, 16);
            if (k < 10) hh += ov * sW[kk * 10 + k];
        }
        if (k >= 10) hh = 0.f;
        float ts = hh * sas[k];
        float td = hh * sad[k];
#pragma unroll
        for (int off = 1; off < 16; off <<= 1) {
            ts += __shfl_xor(ts, off, 16);
            td += __shfl_xor(td, off, 16);
        }
        h2[(size_t)nn * 16 + k] = __float2half_rn(hh);  // zero-padded cols 10..15
        if (k == 0) { s2[nn] = ts; d2[nn] = td; }
        sval = fmaxf(sval, ts);
    }
    float m = sval;
#pragma unroll
    for (int off = 32; off >= 1; off >>= 1) m = fmaxf(m, __shfl_xor(m, off));
    if ((tid & 63) == 0) wm[tid >> 6] = m;
    __syncthreads();
    if (tid == 0) {
        float bmx = fmaxf(fmaxf(wm[0], wm[1]), fmaxf(wm[2], wm[3]));
        atomicMax(gmax2, fenc(bmx));
    }
}

// ---- layer-2 agg (same structure) + norm/bias + MLP head -> out ----
__global__ __launch_bounds__(256) void k_agg2(
    const int* __restrict__ bcur, const unsigned* __restrict__ pairs,
    const int* __restrict__ esrc, const int* __restrict__ edst,
    const float* __restrict__ s2, const float* __restrict__ d2, const __half* __restrict__ h2,
    const float* __restrict__ b2, const float* __restrict__ Wl1, const float* __restrict__ bl1,
    const float* __restrict__ Wl2, const float* __restrict__ bl2,
    const unsigned* __restrict__ gmax2p, float* __restrict__ out, int N, int E)
{
    __shared__ unsigned srt[SCAP];
    __shared__ float accs[HN * 17];
    __shared__ int lcnt[HN];
    __shared__ int lofs[HN + 1];
    __shared__ float dds[HN], mbs[HN];
    __shared__ float sW1[100], sb1[16], sW2[16], sb2g[16];
    __shared__ float sbl2;

    int tid = threadIdx.x;
    int fb = blockIdx.x >> 1;
    int hf = blockIdx.x & 1;
    int node0 = blockIdx.x << 6;
    if (tid < 100) sW1[tid] = Wl1[tid];
    if (tid < 16) {
        sb1[tid]  = (tid < 10) ? bl1[tid] : 0.f;
        sW2[tid]  = (tid < 10) ? Wl2[tid] : 0.f;
        sb2g[tid] = (tid < 10) ? b2[tid]  : 0.f;
    }
    if (tid == 0) sbl2 = bl2[0];
    float g0 = fdec(*gmax2p);
    if (tid < HN) {
        int n = node0 + tid;
        float dd = (n < N) ? d2[n] : 0.f;
        dds[tid] = dd; mbs[tid] = lrelu(g0 + dd);
        lcnt[tid] = 0;
    }
    __syncthreads();

    int rbase = fb * CAPB;
    int cnt = bcur[fb * 16];
    int gg = tid >> 2, q = tid & 3;

    bool ok = (cnt <= CAPB);
    unsigned pe[PESA];
    if (ok) {
#pragma unroll
        for (int u = 0; u < PESA; ++u) {
            int i = tid + u * 256;
            bool v = (i < cnt);
            pe[u] = v ? pairs[rbase + i] : 0u;
            if (v) {
                int dl = (pe[u] >> 17) & (BNODES - 1);
                if ((dl >> 6) == hf) atomicAdd(&lcnt[dl & (HN - 1)], 1);
            }
        }
        __syncthreads();
        if (tid < HN) {
            int c = lcnt[tid];
            int pfx = c;
#pragma unroll
            for (int off = 1; off < 64; off <<= 1) {
                int t = __shfl_up(pfx, off, 64);
                if (tid >= off) pfx += t;
            }
            lofs[tid + 1] = pfx;
            lcnt[tid] = pfx - c;
            if (tid == 0) lofs[0] = 0;
        }
        __syncthreads();
        if (lofs[HN] > SCAP) ok = false;
    }

    if (ok) {
#pragma unroll
        for (int u = 0; u < PESA; ++u) {
            int i = tid + u * 256;
            if (i < cnt) {
                unsigned p = pe[u];
                int dl = (p >> 17) & (BNODES - 1);
                if ((dl >> 6) == hf) {
                    int pos = atomicAdd(&lcnt[dl & (HN - 1)], 1);
                    srt[pos] = p & 0x1FFFF;
                }
            }
        }
        __syncthreads();

        int n = node0 + gg;
        float4 accv; float den;
        if (n < N) {
            float w = __expf(lrelu(s2[n] + dds[gg]) - mbs[gg]);
            float4 hv = ldh4(h2, (size_t)n * 16 + 4 * q);   // zero-padded
            accv = make_float4(w * hv.x, w * hv.y, w * hv.z, w * hv.w);
            den = w;
        } else { accv = make_float4(0.f, 0.f, 0.f, 0.f); den = 0.f; }
        {
            float dd = dds[gg], mb = mbs[gg];
            int j = lofs[gg], j1 = lofs[gg + 1];
            for (; j + 4 <= j1; j += 4) {
                int e0 = srt[j], e1 = srt[j + 1], e2 = srt[j + 2], e3 = srt[j + 3];
                float4 H0 = ldh4(h2, (size_t)e0 * 16 + 4 * q);
                float4 H1 = ldh4(h2, (size_t)e1 * 16 + 4 * q);
                float4 H2 = ldh4(h2, (size_t)e2 * 16 + 4 * q);
                float4 H3 = ldh4(h2, (size_t)e3 * 16 + 4 * q);
                int eq = srt[j + q];
                float wq = __expf(lrelu(s2[eq] + dd) - mb);
                float w0 = __shfl(wq, 0, 4), w1 = __shfl(wq, 1, 4);
                float w2 = __shfl(wq, 2, 4), w3 = __shfl(wq, 3, 4);
                accv.x += w0 * H0.x + w1 * H1.x + w2 * H2.x + w3 * H3.x;
                accv.y += w0 * H0.y + w1 * H1.y + w2 * H2.y + w3 * H3.y;
                accv.z += w0 * H0.z + w1 * H1.z + w2 * H2.z + w3 * H3.z;
                accv.w += w0 * H0.w + w1 * H1.w + w2 * H2.w + w3 * H3.w;
                den += (w0 + w1) + (w2 + w3);
            }
            for (; j < j1; ++j) {
                int e0 = srt[j];
                float w0 = __expf(lrelu(s2[e0] + dd) - mb);
                float4 H0 = ldh4(h2, (size_t)e0 * 16 + 4 * q);
                accv.x += w0 * H0.x; accv.y += w0 * H0.y;
                accv.z += w0 * H0.z; accv.w += w0 * H0.w;
                den += w0;
            }
        }
        accs[gg * 17 + 4 * q + 0] = accv.x;
        accs[gg * 17 + 4 * q + 1] = accv.y;
        accs[gg * 17 + 4 * q + 2] = accv.z;
        accs[gg * 17 + 4 * q + 3] = accv.w;
        if (q == 0) accs[gg * 17 + 16] = den;
        __syncthreads();
    } else {
        for (int i = tid; i < HN * 17; i += 256) accs[i] = 0.f;
        __syncthreads();
        if (tid < HN) {
            int n = node0 + tid;
            if (n < N) {
                float w = __expf(lrelu(s2[n] + dds[tid]) - mbs[tid]);
#pragma unroll
                for (int t = 0; t < 16; ++t)
                    accs[tid * 17 + t] = w * __half2float(h2[(size_t)n * 16 + t]);
                accs[tid * 17 + 16] = w;
            }
        }
        __syncthreads();
        for (int i = tid; i < E; i += 256) {
            int d = edst[i];
            if ((d >> 6) != blockIdx.x) continue;
            int nl = d & (HN - 1), src = esrc[i];
            float w = __expf(lrelu(s2[src] + dds[nl]) - mbs[nl]);
#pragma unroll
            for (int t = 0; t < 16; ++t)
                atomicAdd(&accs[nl * 17 + t], w * __half2float(h2[(size_t)src * 16 + t]));
            atomicAdd(&accs[nl * 17 + 16], w);
        }
        __syncthreads();
    }

    int g = tid >> 4, k = tid & 15;
    bool fk = k < 10;
#pragma unroll
    for (int qq = 0; qq < 4; ++qq) {
        int nl = g * 4 + qq, nn = node0 + nl;
        if (nn >= N) continue;           // group-uniform
        float inv = 1.f / accs[nl * 17 + 16];
        float o = fk ? accs[nl * 17 + k] * inv + sb2g[k] : 0.f;
        float v = sb1[k];
#pragma unroll
        for (int kk = 0; kk < 10; ++kk) {
            float ov = __shfl(o, kk, 16);
            if (fk) v += ov * sW1[kk * 10 + k];
        }
        float t = fmaxf(v, 0.f);
        float cc = t * sW2[k];           // zero for k>=10
#pragma unroll
        for (int off = 1; off < 16; off <<= 1) cc += __shfl_xor(cc, off, 16);
        if (k == 0) out[nn] = cc + sbl2;
    }
}

extern "C" void kernel_launch(void* const* d_in, const int* in_sizes, int n_in,
                              void* d_out, int out_size, void* d_ws, size_t ws_size,
                              hipStream_t stream)
{
    const float* x   = (const float*)d_in[0];
    const int*   ei  = (const int*)  d_in[1];   // [2][E] int32
    const float* W1  = (const float*)d_in[2];
    const float* a1s = (const float*)d_in[3];
    const float* a1d = (const float*)d_in[4];
    const float* b1  = (const float*)d_in[5];
    const float* W2  = (const float*)d_in[6];
    const float* a2s = (const float*)d_in[7];
    const float* a2d = (const float*)d_in[8];
    const float* b2  = (const float*)d_in[9];
    const float* Wl1 = (const float*)d_in[10];
    const float* bl1 = (const float*)d_in[11];
    const float* Wl2 = (const float*)d_in[12];
    const float* bl2 = (const float*)d_in[13];

    int N = in_sizes[0] / 128;
    int E = in_sizes[1] / 2;
    const int* ei_src = ei;
    const int* ei_dst = ei + E;
    int NSB = (N + BNODES - 1) >> FSH;       // 782 buckets (<= NSBMAX)

    size_t Np = ((size_t)N + 3) & ~(size_t)3;
    size_t need_bytes = (16 + (size_t)NSB * 16) * 4 + Np * 20 * 4 + (size_t)NSB * CAPB * 4;
    if (ws_size < need_bytes) return;  // degrade to wrong-answer, never fault

    // layout: [gmax1 gmax2 pad..16][bcur NSB*16][h1 s1 d1 h2 s2 d2][pairs]
    unsigned* gmax1 = (unsigned*)d_ws;       // [0]
    unsigned* gmax2 = gmax1 + 1;             // [1]
    int* bcur = (int*)d_ws + 16;             // NSB*16 (1 cursor per 64B), RELATIVE
    float* rest = (float*)d_ws + 16 + (size_t)NSB * 16;
    __half* h1 = (__half*)rest;              // Np*16 halves
    float* s1 = rest + Np * 8;               // Np
    float* d1 = s1 + Np;                     // Np
    __half* h2 = (__half*)(d1 + Np);         // Np*16 halves (cols 10..15 zero)
    float* s2 = (float*)(h2) + Np * 8;       // Np
    float* d2 = s2 + Np;                     // Np
    unsigned* pairs = (unsigned*)(d2 + Np);  // NSB*CAPB

    int NG = (N + 63) / 64;
    int NC = (E + TILE - 1) / TILE;

    // zero gmax + relative bucket cursors in one memset (replaces k_init)
    hipMemsetAsync(d_ws, 0, (16 + (size_t)NSB * 16) * sizeof(int), stream);
    hipLaunchKernelGGL(k_front, dim3(NG + NC), dim3(256), 0, stream,
                       x, W1, a1s, a1d, h1, s1, d1, gmax1,
                       ei_src, ei_dst, bcur, pairs, N, E, NG, NC, NSB);
    hipLaunchKernelGGL(k_agg1, dim3(NSB * 2), dim3(256), 0, stream,
                       bcur, pairs, ei_src, ei_dst, s1, d1, h1, b1, W2, a2s, a2d,
                       h2, s2, d2, gmax1, gmax2, N, E);
    hipLaunchKernelGGL(k_agg2, dim3(NSB * 2), dim3(256), 0, stream,
                       bcur, pairs, ei_src, ei_dst, s2, d2, h2, b2, Wl1, bl1, Wl2, bl2,
                       gmax2, (float*)d_out, N, E);
}

// Round 6
// 274.362 us; speedup vs baseline: 1.0410x; 1.0080x over previous
//
#include <hip/hip_runtime.h>
#include <hip/hip_fp16.h>
#include <hip/hip_cooperative_groups.h>

namespace cg = cooperative_groups;

// GAT (2 layers, heads=1) + 2-layer MLP head. N=100000, E=3200000, D=128.
// R21 = R20 front + FUSED cooperative agg: agg1+agg2 in one kernel with
// grid.sync between layers. The dst-sorted srt/lofs built in phase A stays
// resident in LDS, so phase B (layer 2) skips the pairs re-read and the
// two LDS-atomic sort passes entirely. Host-side occupancy check + launch
// error check fall back to the proven two-kernel path.
// Overflow -> full-rescan fallback keeps arbitrary inputs correct.
// Softmax stabilization uses a GLOBAL upper bound m̄_i = leaky(gmax_asrc+adst_i)
// (valid since leaky_relu is monotone); alpha is mathematically unchanged.

#define NEG 0.2f
#define FSH 7
#define BNODES 128           // nodes per bucket
#define NSBMAX 1024          // >= ceil(100000/128)=782
#define CAPB 4608            // per-bucket region capacity (mean 4096, +8 sigma)
#define TILE 4096            // edges per csplit block (256 threads, 16/thread)
#define EPT 16               // TILE/256 register-staged edges per thread
#define HN 64                // nodes per agg half-block
#define SCAP 3072            // per-half srt capacity (mean 2048, +22 sigma)
#define PESA 18              // ceil(CAPB/256) register-staged pairs per thread

__device__ __forceinline__ float lrelu(float x) { return x > 0.0f ? x : NEG * x; }

__device__ __forceinline__ unsigned fenc(float f) {
    unsigned u = __float_as_uint(f);
    return (u & 0x80000000u) ? ~u : (u | 0x80000000u);
}
__device__ __forceinline__ float fdec(unsigned e) {
    return (e & 0x80000000u) ? __uint_as_float(e & 0x7FFFFFFFu) : __uint_as_float(~e);
}

// load 4 consecutive halves as float4 (8B load)
__device__ __forceinline__ float4 ldh4(const __half* h, size_t off) {
    uint2 u = *(const uint2*)(h + off);
    __half2 a = *(__half2*)&u.x, b = *(__half2*)&u.y;
    float2 fa = __half22float2(a), fb = __half22float2(b);
    return make_float4(fa.x, fa.y, fb.x, fb.y);
}

// ---- fused front-end: gemm role + csplit role in one grid (R20) ----
__global__ __launch_bounds__(256) void k_front(
    const float* __restrict__ x, const float* __restrict__ W1,
    const float* __restrict__ a1s, const float* __restrict__ a1d,
    __half* __restrict__ h1, float* __restrict__ s1, float* __restrict__ d1,
    unsigned* __restrict__ gmax,
    const int* __restrict__ esrc, const int* __restrict__ edst,
    int* __restrict__ bcur, unsigned* __restrict__ pairs,
    int N, int E, int NG, int NC, int NSB)
{
    __shared__ float smem[9220];
    int tid = threadIdx.x;
    int bid = blockIdx.x;
    long long T = (long long)NG + NC;
    int before = (int)(((long long)bid * NC) / T);
    int isc = (int)((((long long)bid + 1) * NC) / T) > before;

    if (isc) {
        unsigned* lsrt = (unsigned*)smem;                   // TILE
        int* lhist = (int*)smem + TILE;                     // 1024
        int* lofs  = lhist + NSBMAX;                        // 1024
        int* gbase = lofs + NSBMAX;                         // 1024
        int* wsum  = gbase + NSBMAX;                        // 4
        unsigned short* rid = (unsigned short*)(smem + TILE + 3 * NSBMAX + 4);
        int cid = before;
        int base = cid * TILE;
        int tcnt = min(TILE, E - base);
        for (int i = tid; i < NSB; i += 256) lhist[i] = 0;
        __syncthreads();
        int ed[EPT];
#pragma unroll
        for (int u = 0; u < EPT; ++u) {
            int i = tid + u * 256;
            ed[u] = (i < tcnt) ? edst[base + i] : -1;
            if (ed[u] >= 0) atomicAdd(&lhist[ed[u] >> FSH], 1);
        }
        __syncthreads();
        int i0 = 4 * tid;
        int a0 = (i0 + 0 < NSB) ? lhist[i0 + 0] : 0;
        int a1 = (i0 + 1 < NSB) ? lhist[i0 + 1] : 0;
        int a2 = (i0 + 2 < NSB) ? lhist[i0 + 2] : 0;
        int a3 = (i0 + 3 < NSB) ? lhist[i0 + 3] : 0;
        int s = a0 + a1 + a2 + a3, pfx = s;
#pragma unroll
        for (int off = 1; off < 64; off <<= 1) {
            int t = __shfl_up(pfx, off, 64);
            if ((tid & 63) >= off) pfx += t;
        }
        if ((tid & 63) == 63) wsum[tid >> 6] = pfx;
        __syncthreads();
        int carry = 0;
        for (int w = 0; w < (tid >> 6); ++w) carry += wsum[w];
        int excl = pfx + carry - s;
        if (i0 + 0 < NSB) { lofs[i0 + 0] = excl;                 gbase[i0 + 0] = a0 ? atomicAdd(&bcur[(i0 + 0) * 16], a0) : 0; }
        if (i0 + 1 < NSB) { lofs[i0 + 1] = excl + a0;            gbase[i0 + 1] = a1 ? atomicAdd(&bcur[(i0 + 1) * 16], a1) : 0; }
        if (i0 + 2 < NSB) { lofs[i0 + 2] = excl + a0 + a1;       gbase[i0 + 2] = a2 ? atomicAdd(&bcur[(i0 + 2) * 16], a2) : 0; }
        if (i0 + 3 < NSB) { lofs[i0 + 3] = excl + a0 + a1 + a2;  gbase[i0 + 3] = a3 ? atomicAdd(&bcur[(i0 + 3) * 16], a3) : 0; }
        __syncthreads();
        if (i0 + 0 < NSB) lhist[i0 + 0] = lofs[i0 + 0];
        if (i0 + 1 < NSB) lhist[i0 + 1] = lofs[i0 + 1];
        if (i0 + 2 < NSB) lhist[i0 + 2] = lofs[i0 + 2];
        if (i0 + 3 < NSB) lhist[i0 + 3] = lofs[i0 + 3];
        __syncthreads();
#pragma unroll
        for (int u = 0; u < EPT; ++u) {
            int i = tid + u * 256;
            if (ed[u] >= 0) {
                int d = ed[u], srcv = esrc[base + i];
                int b = d >> FSH;
                int pos = atomicAdd(&lhist[b], 1);
                lsrt[pos] = ((unsigned)(d & (BNODES - 1)) << 17) | (unsigned)srcv;
                rid[pos] = (unsigned short)b;
            }
        }
        __syncthreads();
        for (int i = tid; i < tcnt; i += 256) {
            int r = rid[i];
            int rel = gbase[r] + (i - lofs[r]);
            if (rel < CAPB) pairs[(size_t)r * CAPB + rel] = lsrt[i];
        }
        return;
    }

    // gemm role (no x stage; j-partitioned lanes)
    float* sW = smem;
    float* wm = smem + 2060;
    int gid = bid - before;
    for (int i = tid; i < 2048; i += 256) sW[i + ((i >> 9) << 2)] = W1[i];
    int node0 = gid * 64;
    int node = node0 + (tid >> 2);
    int q = tid & 3;
    bool valid = node < N;
    float4 xr[8];
    {
        const float4* xp = (const float4*)x + (size_t)node * 32 + q * 8;
#pragma unroll
        for (int k = 0; k < 8; ++k)
            xr[k] = valid ? xp[k] : make_float4(0.f, 0.f, 0.f, 0.f);
    }
    __syncthreads();

    float acc[16];
#pragma unroll
    for (int c = 0; c < 16; ++c) acc[c] = 0.f;
    int wbase = q * 516;
#pragma unroll
    for (int k = 0; k < 8; ++k) {
        float xs0 = xr[k].x, xs1 = xr[k].y, xs2 = xr[k].z, xs3 = xr[k].w;
#pragma unroll
        for (int t = 0; t < 4; ++t) {
            float xv = (t == 0) ? xs0 : (t == 1) ? xs1 : (t == 2) ? xs2 : xs3;
            const float4* wrow = (const float4*)&sW[wbase + (k * 4 + t) * 16];
            float4 w0 = wrow[0], w1 = wrow[1], w2 = wrow[2], w3 = wrow[3];
            acc[0]  += xv * w0.x; acc[1]  += xv * w0.y; acc[2]  += xv * w0.z; acc[3]  += xv * w0.w;
            acc[4]  += xv * w1.x; acc[5]  += xv * w1.y; acc[6]  += xv * w1.z; acc[7]  += xv * w1.w;
            acc[8]  += xv * w2.x; acc[9]  += xv * w2.y; acc[10] += xv * w2.z; acc[11] += xv * w2.w;
            acc[12] += xv * w3.x; acc[13] += xv * w3.y; acc[14] += xv * w3.z; acc[15] += xv * w3.w;
        }
    }
#pragma unroll
    for (int c = 0; c < 16; ++c) {
        acc[c] += __shfl_xor(acc[c], 1);
        acc[c] += __shfl_xor(acc[c], 2);
    }
    float sv = 0.f, dv = 0.f;
    {
        const float4* asp = (const float4*)a1s;
        const float4* adp = (const float4*)a1d;
#pragma unroll
        for (int r = 0; r < 4; ++r) {
            float4 as = asp[r], ad = adp[r];
            sv += acc[r*4+0]*as.x + acc[r*4+1]*as.y + acc[r*4+2]*as.z + acc[r*4+3]*as.w;
            dv += acc[r*4+0]*ad.x + acc[r*4+1]*ad.y + acc[r*4+2]*ad.z + acc[r*4+3]*ad.w;
        }
    }
    if (valid) {
        float4 av;
        if      (q == 0) av = make_float4(acc[0],  acc[1],  acc[2],  acc[3]);
        else if (q == 1) av = make_float4(acc[4],  acc[5],  acc[6],  acc[7]);
        else if (q == 2) av = make_float4(acc[8],  acc[9],  acc[10], acc[11]);
        else             av = make_float4(acc[12], acc[13], acc[14], acc[15]);
        __half2 p0 = __floats2half2_rn(av.x, av.y);
        __half2 p1 = __floats2half2_rn(av.z, av.w);
        uint2 u; u.x = *(unsigned*)&p0; u.y = *(unsigned*)&p1;
        *(uint2*)&h1[(size_t)node * 16 + q * 4] = u;
        if (q == 0) { s1[node] = sv; d1[node] = dv; }
    }
    float m = valid ? sv : -3.4e38f;
#pragma unroll
    for (int off = 32; off >= 1; off >>= 1) m = fmaxf(m, __shfl_xor(m, off));
    if ((tid & 63) == 0) wm[tid >> 6] = m;
    __syncthreads();
    if (tid == 0) {
        float b = fmaxf(fmaxf(wm[0], wm[1]), fmaxf(wm[2], wm[3]));
        atomicMax(gmax, fenc(b));
    }
}

// ---- FUSED agg (cooperative): phase A = layer1, grid.sync, phase B = layer2
// reusing the LDS-resident srt/lofs (no re-read, no re-sort). ----
__global__ __launch_bounds__(256, 7) void k_aggf(
    const int* __restrict__ bcur, const unsigned* __restrict__ pairs,
    const int* __restrict__ esrc, const int* __restrict__ edst,
    const float* __restrict__ s1, const float* __restrict__ d1, const __half* __restrict__ h1,
    const float* __restrict__ b1, const float* __restrict__ W2,
    const float* __restrict__ a2s, const float* __restrict__ a2d,
    __half* __restrict__ h2, float* __restrict__ s2, float* __restrict__ d2,
    const unsigned* __restrict__ gmax1p, unsigned* __restrict__ gmax2,
    const float* __restrict__ b2, const float* __restrict__ Wl1, const float* __restrict__ bl1,
    const float* __restrict__ Wl2, const float* __restrict__ bl2,
    float* __restrict__ out, int N, int E)
{
    __shared__ unsigned srt[SCAP];
    __shared__ float accs[HN * 17];
    __shared__ int lcnt[HN];
    __shared__ int lofs[HN + 1];
    __shared__ float dds[HN], mbs[HN];
    __shared__ float sW[160], sb[16], sas[16], sad[16];
    __shared__ float sW1[100], sb1[16], sW2[16], sb2g[16];
    __shared__ float sbl2;
    __shared__ float wm[4];
    __shared__ int s_ok;

    int tid = threadIdx.x;
    int fb = blockIdx.x >> 1;
    int hf = blockIdx.x & 1;
    int node0 = blockIdx.x << 6;
    if (tid < 160) sW[tid] = W2[tid];
    if (tid < 100) sW1[tid] = Wl1[tid];
    if (tid < 16) {
        sb[tid]   = b1[tid];
        sas[tid]  = (tid < 10) ? a2s[tid] : 0.f;
        sad[tid]  = (tid < 10) ? a2d[tid] : 0.f;
        sb1[tid]  = (tid < 10) ? bl1[tid] : 0.f;
        sW2[tid]  = (tid < 10) ? Wl2[tid] : 0.f;
        sb2g[tid] = (tid < 10) ? b2[tid]  : 0.f;
    }
    if (tid == 0) sbl2 = bl2[0];
    float g0 = fdec(*gmax1p);
    if (tid < HN) {
        int n = node0 + tid;
        float dd = (n < N) ? d1[n] : 0.f;
        dds[tid] = dd; mbs[tid] = lrelu(g0 + dd);
        lcnt[tid] = 0;
    }
    __syncthreads();

    int rbase = fb * CAPB;
    int cnt = bcur[fb * 16];             // RELATIVE count; > CAPB means overflow
    int gg = tid >> 2, q = tid & 3;      // 64 groups x 4 lanes, 1 node each

    // ---------------- phase A: layer-1 sort + gather ----------------
    bool ok = (cnt <= CAPB);
    if (ok) {
        unsigned pe[PESA];
#pragma unroll
        for (int u = 0; u < PESA; ++u) {
            int i = tid + u * 256;
            bool v = (i < cnt);
            pe[u] = v ? pairs[rbase + i] : 0u;
            if (v) {
                int dl = (pe[u] >> 17) & (BNODES - 1);
                if ((dl >> 6) == hf) atomicAdd(&lcnt[dl & (HN - 1)], 1);
            }
        }
        __syncthreads();
        if (tid < HN) {
            int c = lcnt[tid];
            int pfx = c;
#pragma unroll
            for (int off = 1; off < 64; off <<= 1) {
                int t = __shfl_up(pfx, off, 64);
                if (tid >= off) pfx += t;
            }
            lofs[tid + 1] = pfx;
            lcnt[tid] = pfx - c;
            if (tid == 0) lofs[0] = 0;
        }
        __syncthreads();
        if (lofs[HN] > SCAP) ok = false;
        if (ok) {
#pragma unroll
            for (int u = 0; u < PESA; ++u) {
                int i = tid + u * 256;
                if (i < cnt) {
                    unsigned p = pe[u];
                    int dl = (p >> 17) & (BNODES - 1);
                    if ((dl >> 6) == hf) {
                        int pos = atomicAdd(&lcnt[dl & (HN - 1)], 1);
                        srt[pos] = p & 0x1FFFF;
                    }
                }
            }
        }
    }
    if (tid == 0) s_ok = ok ? 1 : 0;
    __syncthreads();

    if (s_ok) {
        int n = node0 + gg;
        float4 accv; float den;
        if (n < N) {
            float w = __expf(lrelu(s1[n] + dds[gg]) - mbs[gg]);
            float4 hv = ldh4(h1, (size_t)n * 16 + 4 * q);
            accv = make_float4(w * hv.x, w * hv.y, w * hv.z, w * hv.w);
            den = w;
        } else { accv = make_float4(0.f, 0.f, 0.f, 0.f); den = 0.f; }
        {
            float dd = dds[gg], mb = mbs[gg];
            int j = lofs[gg], j1 = lofs[gg + 1];
            for (; j + 4 <= j1; j += 4) {
                int e0 = srt[j], e1 = srt[j + 1], e2 = srt[j + 2], e3 = srt[j + 3];
                float4 H0 = ldh4(h1, (size_t)e0 * 16 + 4 * q);
                float4 H1 = ldh4(h1, (size_t)e1 * 16 + 4 * q);
                float4 H2 = ldh4(h1, (size_t)e2 * 16 + 4 * q);
                float4 H3 = ldh4(h1, (size_t)e3 * 16 + 4 * q);
                int eq = srt[j + q];
                float wq = __expf(lrelu(s1[eq] + dd) - mb);
                float w0 = __shfl(wq, 0, 4), w1 = __shfl(wq, 1, 4);
                float w2 = __shfl(wq, 2, 4), w3 = __shfl(wq, 3, 4);
                accv.x += w0 * H0.x + w1 * H1.x + w2 * H2.x + w3 * H3.x;
                accv.y += w0 * H0.y + w1 * H1.y + w2 * H2.y + w3 * H3.y;
                accv.z += w0 * H0.z + w1 * H1.z + w2 * H2.z + w3 * H3.z;
                accv.w += w0 * H0.w + w1 * H1.w + w2 * H2.w + w3 * H3.w;
                den += (w0 + w1) + (w2 + w3);
            }
            for (; j < j1; ++j) {
                int e0 = srt[j];
                float w0 = __expf(lrelu(s1[e0] + dd) - mb);
                float4 H0 = ldh4(h1, (size_t)e0 * 16 + 4 * q);
                accv.x += w0 * H0.x; accv.y += w0 * H0.y;
                accv.z += w0 * H0.z; accv.w += w0 * H0.w;
                den += w0;
            }
        }
        accs[gg * 17 + 4 * q + 0] = accv.x;
        accs[gg * 17 + 4 * q + 1] = accv.y;
        accs[gg * 17 + 4 * q + 2] = accv.z;
        accs[gg * 17 + 4 * q + 3] = accv.w;
        if (q == 0) accs[gg * 17 + 16] = den;
        __syncthreads();
    } else {
        for (int i = tid; i < HN * 17; i += 256) accs[i] = 0.f;
        __syncthreads();
        if (tid < HN) {
            int n = node0 + tid;
            if (n < N) {
                float w = __expf(lrelu(s1[n] + dds[tid]) - mbs[tid]);
#pragma unroll
                for (int t = 0; t < 16; ++t)
                    accs[tid * 17 + t] = w * __half2float(h1[(size_t)n * 16 + t]);
                accs[tid * 17 + 16] = w;
            }
        }
        __syncthreads();
        for (int i = tid; i < E; i += 256) {
            int d = edst[i];
            if ((d >> 6) != blockIdx.x) continue;
            int nl = d & (HN - 1), src = esrc[i];
            float w = __expf(lrelu(s1[src] + dds[nl]) - mbs[nl]);
#pragma unroll
            for (int t = 0; t < 16; ++t)
                atomicAdd(&accs[nl * 17 + t], w * __half2float(h1[(size_t)src * 16 + t]));
            atomicAdd(&accs[nl * 17 + 16], w);
        }
        __syncthreads();
    }

    // layer-1 epilogue -> h2/s2/d2 + gmax2
    {
        int g = tid >> 4, k = tid & 15;
        float sval = -3.4e38f;
#pragma unroll
        for (int qq = 0; qq < 4; ++qq) {
            int nl = g * 4 + qq, nn = node0 + nl;
            if (nn >= N) continue;           // group-uniform
            float inv = 1.f / accs[nl * 17 + 16];
            float o = fmaxf(accs[nl * 17 + k] * inv + sb[k], 0.f);
            float hh = 0.f;
#pragma unroll
            for (int kk = 0; kk < 16; ++kk) {
                float ov = __shfl(o, kk, 16);
                if (k < 10) hh += ov * sW[kk * 10 + k];
            }
            if (k >= 10) hh = 0.f;
            float ts = hh * sas[k];
            float td = hh * sad[k];
#pragma unroll
            for (int off = 1; off < 16; off <<= 1) {
                ts += __shfl_xor(ts, off, 16);
                td += __shfl_xor(td, off, 16);
            }
            h2[(size_t)nn * 16 + k] = __float2half_rn(hh);  // zero-padded cols 10..15
            if (k == 0) { s2[nn] = ts; d2[nn] = td; }
            sval = fmaxf(sval, ts);
        }
        float m = sval;
#pragma unroll
        for (int off = 32; off >= 1; off >>= 1) m = fmaxf(m, __shfl_xor(m, off));
        if ((tid & 63) == 0) wm[tid >> 6] = m;
        __syncthreads();
        if (tid == 0) {
            float bmx = fmaxf(fmaxf(wm[0], wm[1]), fmaxf(wm[2], wm[3]));
            atomicMax(gmax2, fenc(bmx));
        }
    }

    // ---------------- grid-wide barrier ----------------
    cg::this_grid().sync();

    // ---------------- phase B: layer-2 gather (srt/lofs reused) ----------------
    float g2 = fdec(*(const volatile unsigned*)gmax2);
    if (tid < HN) {
        int n = node0 + tid;
        float dd = (n < N) ? d2[n] : 0.f;
        dds[tid] = dd; mbs[tid] = lrelu(g2 + dd);
    }
    __syncthreads();

    if (s_ok) {
        int n = node0 + gg;
        float4 accv; float den;
        if (n < N) {
            float w = __expf(lrelu(s2[n] + dds[gg]) - mbs[gg]);
            float4 hv = ldh4(h2, (size_t)n * 16 + 4 * q);   // zero-padded
            accv = make_float4(w * hv.x, w * hv.y, w * hv.z, w * hv.w);
            den = w;
        } else { accv = make_float4(0.f, 0.f, 0.f, 0.f); den = 0.f; }
        {
            float dd = dds[gg], mb = mbs[gg];
            int j = lofs[gg], j1 = lofs[gg + 1];
            for (; j + 4 <= j1; j += 4) {
                int e0 = srt[j], e1 = srt[j + 1], e2 = srt[j + 2], e3 = srt[j + 3];
                float4 H0 = ldh4(h2, (size_t)e0 * 16 + 4 * q);
                float4 H1 = ldh4(h2, (size_t)e1 * 16 + 4 * q);
                float4 H2 = ldh4(h2, (size_t)e2 * 16 + 4 * q);
                float4 H3 = ldh4(h2, (size_t)e3 * 16 + 4 * q);
                int eq = srt[j + q];
                float wq = __expf(lrelu(s2[eq] + dd) - mb);
                float w0 = __shfl(wq, 0, 4), w1 = __shfl(wq, 1, 4);
                float w2 = __shfl(wq, 2, 4), w3 = __shfl(wq, 3, 4);
                accv.x += w0 * H0.x + w1 * H1.x + w2 * H2.x + w3 * H3.x;
                accv.y += w0 * H0.y + w1 * H1.y + w2 * H2.y + w3 * H3.y;
                accv.z += w0 * H0.z + w1 * H1.z + w2 * H2.z + w3 * H3.z;
                accv.w += w0 * H0.w + w1 * H1.w + w2 * H2.w + w3 * H3.w;
                den += (w0 + w1) + (w2 + w3);
            }
            for (; j < j1; ++j) {
                int e0 = srt[j];
                float w0 = __expf(lrelu(s2[e0] + dd) - mb);
                float4 H0 = ldh4(h2, (size_t)e0 * 16 + 4 * q);
                accv.x += w0 * H0.x; accv.y += w0 * H0.y;
                accv.z += w0 * H0.z; accv.w += w0 * H0.w;
                den += w0;
            }
        }
        __syncthreads();     // accs free (phase A epilogue done for all threads)
        accs[gg * 17 + 4 * q + 0] = accv.x;
        accs[gg * 17 + 4 * q + 1] = accv.y;
        accs[gg * 17 + 4 * q + 2] = accv.z;
        accs[gg * 17 + 4 * q + 3] = accv.w;
        if (q == 0) accs[gg * 17 + 16] = den;
        __syncthreads();
    } else {
        for (int i = tid; i < HN * 17; i += 256) accs[i] = 0.f;
        __syncthreads();
        if (tid < HN) {
            int n = node0 + tid;
            if (n < N) {
                float w = __expf(lrelu(s2[n] + dds[tid]) - mbs[tid]);
#pragma unroll
                for (int t = 0; t < 16; ++t)
                    accs[tid * 17 + t] = w * __half2float(h2[(size_t)n * 16 + t]);
                accs[tid * 17 + 16] = w;
            }
        }
        __syncthreads();
        for (int i = tid; i < E; i += 256) {
            int d = edst[i];
            if ((d >> 6) != blockIdx.x) continue;
            int nl = d & (HN - 1), src = esrc[i];
            float w = __expf(lrelu(s2[src] + dds[nl]) - mbs[nl]);
#pragma unroll
            for (int t = 0; t < 16; ++t)
                atomicAdd(&accs[nl * 17 + t], w * __half2float(h2[(size_t)src * 16 + t]));
            atomicAdd(&accs[nl * 17 + 16], w);
        }
        __syncthreads();
    }

    // layer-2 epilogue: norm/bias + MLP head -> out
    {
        int g = tid >> 4, k = tid & 15;
        bool fk = k < 10;
#pragma unroll
        for (int qq = 0; qq < 4; ++qq) {
            int nl = g * 4 + qq, nn = node0 + nl;
            if (nn >= N) continue;           // group-uniform
            float inv = 1.f / accs[nl * 17 + 16];
            float o = fk ? accs[nl * 17 + k] * inv + sb2g[k] : 0.f;
            float v = sb1[k];
#pragma unroll
            for (int kk = 0; kk < 10; ++kk) {
                float ov = __shfl(o, kk, 16);
                if (fk) v += ov * sW1[kk * 10 + k];
            }
            float t = fmaxf(v, 0.f);
            float cc = t * sW2[k];           // zero for k>=10
#pragma unroll
            for (int off = 1; off < 16; off <<= 1) cc += __shfl_xor(cc, off, 16);
            if (k == 0) out[nn] = cc + sbl2;
        }
    }
}

// ---- legacy two-kernel agg path (fallback if cooperative not possible) ----
__global__ __launch_bounds__(256) void k_agg1(
    const int* __restrict__ bcur, const unsigned* __restrict__ pairs,
    const int* __restrict__ esrc, const int* __restrict__ edst,
    const float* __restrict__ s1, const float* __restrict__ d1, const __half* __restrict__ h1,
    const float* __restrict__ b1, const float* __restrict__ W2,
    const float* __restrict__ a2s, const float* __restrict__ a2d,
    __half* __restrict__ h2, float* __restrict__ s2, float* __restrict__ d2,
    const unsigned* __restrict__ gmax1p, unsigned* __restrict__ gmax2, int N, int E)
{
    __shared__ unsigned srt[SCAP];
    __shared__ float accs[HN * 17];
    __shared__ int lcnt[HN];
    __shared__ int lofs[HN + 1];
    __shared__ float dds[HN], mbs[HN];
    __shared__ float sW[160], sb[16], sas[16], sad[16];
    __shared__ float wm[4];

    int tid = threadIdx.x;
    int fb = blockIdx.x >> 1;
    int hf = blockIdx.x & 1;
    int node0 = blockIdx.x << 6;
    if (tid < 160) sW[tid] = W2[tid];
    if (tid < 16) {
        sb[tid]  = b1[tid];
        sas[tid] = (tid < 10) ? a2s[tid] : 0.f;
        sad[tid] = (tid < 10) ? a2d[tid] : 0.f;
    }
    float g0 = fdec(*gmax1p);
    if (tid < HN) {
        int n = node0 + tid;
        float dd = (n < N) ? d1[n] : 0.f;
        dds[tid] = dd; mbs[tid] = lrelu(g0 + dd);
        lcnt[tid] = 0;
    }
    __syncthreads();

    int rbase = fb * CAPB;
    int cnt = bcur[fb * 16];
    int gg = tid >> 2, q = tid & 3;

    bool ok = (cnt <= CAPB);
    unsigned pe[PESA];
    if (ok) {
#pragma unroll
        for (int u = 0; u < PESA; ++u) {
            int i = tid + u * 256;
            bool v = (i < cnt);
            pe[u] = v ? pairs[rbase + i] : 0u;
            if (v) {
                int dl = (pe[u] >> 17) & (BNODES - 1);
                if ((dl >> 6) == hf) atomicAdd(&lcnt[dl & (HN - 1)], 1);
            }
        }
        __syncthreads();
        if (tid < HN) {
            int c = lcnt[tid];
            int pfx = c;
#pragma unroll
            for (int off = 1; off < 64; off <<= 1) {
                int t = __shfl_up(pfx, off, 64);
                if (tid >= off) pfx += t;
            }
            lofs[tid + 1] = pfx;
            lcnt[tid] = pfx - c;
            if (tid == 0) lofs[0] = 0;
        }
        __syncthreads();
        if (lofs[HN] > SCAP) ok = false;
    }

    if (ok) {
#pragma unroll
        for (int u = 0; u < PESA; ++u) {
            int i = tid + u * 256;
            if (i < cnt) {
                unsigned p = pe[u];
                int dl = (p >> 17) & (BNODES - 1);
                if ((dl >> 6) == hf) {
                    int pos = atomicAdd(&lcnt[dl & (HN - 1)], 1);
                    srt[pos] = p & 0x1FFFF;
                }
            }
        }
        __syncthreads();

        int n = node0 + gg;
        float4 accv; float den;
        if (n < N) {
            float w = __expf(lrelu(s1[n] + dds[gg]) - mbs[gg]);
            float4 hv = ldh4(h1, (size_t)n * 16 + 4 * q);
            accv = make_float4(w * hv.x, w * hv.y, w * hv.z, w * hv.w);
            den = w;
        } else { accv = make_float4(0.f, 0.f, 0.f, 0.f); den = 0.f; }
        {
            float dd = dds[gg], mb = mbs[gg];
            int j = lofs[gg], j1 = lofs[gg + 1];
            for (; j + 4 <= j1; j += 4) {
                int e0 = srt[j], e1 = srt[j + 1], e2 = srt[j + 2], e3 = srt[j + 3];
                float4 H0 = ldh4(h1, (size_t)e0 * 16 + 4 * q);
                float4 H1 = ldh4(h1, (size_t)e1 * 16 + 4 * q);
                float4 H2 = ldh4(h1, (size_t)e2 * 16 + 4 * q);
                float4 H3 = ldh4(h1, (size_t)e3 * 16 + 4 * q);
                int eq = srt[j + q];
                float wq = __expf(lrelu(s1[eq] + dd) - mb);
                float w0 = __shfl(wq, 0, 4), w1 = __shfl(wq, 1, 4);
                float w2 = __shfl(wq, 2, 4), w3 = __shfl(wq, 3, 4);
                accv.x += w0 * H0.x + w1 * H1.x + w2 * H2.x + w3 * H3.x;
                accv.y += w0 * H0.y + w1 * H1.y + w2 * H2.y + w3 * H3.y;
                accv.z += w0 * H0.z + w1 * H1.z + w2 * H2.z + w3 * H3.z;
                accv.w += w0 * H0.w + w1 * H1.w + w2 * H2.w + w3 * H3.w;
                den += (w0 + w1) + (w2 + w3);
            }
            for (; j < j1; ++j) {
                int e0 = srt[j];
                float w0 = __expf(lrelu(s1[e0] + dd) - mb);
                float4 H0 = ldh4(h1, (size_t)e0 * 16 + 4 * q);
                accv.x += w0 * H0.x; accv.y += w0 * H0.y;
                accv.z += w0 * H0.z; accv.w += w0 * H0.w;
                den += w0;
            }
        }
        accs[gg * 17 + 4 * q + 0] = accv.x;
        accs[gg * 17 + 4 * q + 1] = accv.y;
        accs[gg * 17 + 4 * q + 2] = accv.z;
        accs[gg * 17 + 4 * q + 3] = accv.w;
        if (q == 0) accs[gg * 17 + 16] = den;
        __syncthreads();
    } else {
        for (int i = tid; i < HN * 17; i += 256) accs[i] = 0.f;
        __syncthreads();
        if (tid < HN) {
            int n = node0 + tid;
            if (n < N) {
                float w = __expf(lrelu(s1[n] + dds[tid]) - mbs[tid]);
#pragma unroll
                for (int t = 0; t < 16; ++t)
                    accs[tid * 17 + t] = w * __half2float(h1[(size_t)n * 16 + t]);
                accs[tid * 17 + 16] = w;
            }
        }
        __syncthreads();
        for (int i = tid; i < E; i += 256) {
            int d = edst[i];
            if ((d >> 6) != blockIdx.x) continue;
            int nl = d & (HN - 1), src = esrc[i];
            float w = __expf(lrelu(s1[src] + dds[nl]) - mbs[nl]);
#pragma unroll
            for (int t = 0; t < 16; ++t)
                atomicAdd(&accs[nl * 17 + t], w * __half2float(h1[(size_t)src * 16 + t]));
            atomicAdd(&accs[nl * 17 + 16], w);
        }
        __syncthreads();
    }

    int g = tid >> 4, k = tid & 15;
    float sval = -3.4e38f;
#pragma unroll
    for (int qq = 0; qq < 4; ++qq) {
        int nl = g * 4 + qq, nn = node0 + nl;
        if (nn >= N) continue;
        float inv = 1.f / accs[nl * 17 + 16];
        float o = fmaxf(accs[nl * 17 + k] * inv + sb[k], 0.f);
        float hh = 0.f;
#pragma unroll
        for (int kk = 0; kk < 16; ++kk) {
            float ov = __shfl(o, kk, 16);
            if (k < 10) hh += ov * sW[kk * 10 + k];
        }
        if (k >= 10) hh = 0.f;
        float ts = hh * sas[k];
        float td = hh * sad[k];
#pragma unroll
        for (int off = 1; off < 16; off <<= 1) {
            ts += __shfl_xor(ts, off, 16);
            td += __shfl_xor(td, off, 16);
        }
        h2[(size_t)nn * 16 + k] = __float2half_rn(hh);
        if (k == 0) { s2[nn] = ts; d2[nn] = td; }
        sval = fmaxf(sval, ts);
    }
    float m = sval;
#pragma unroll
    for (int off = 32; off >= 1; off >>= 1) m = fmaxf(m, __shfl_xor(m, off));
    if ((tid & 63) == 0) wm[tid >> 6] = m;
    __syncthreads();
    if (tid == 0) {
        float bmx = fmaxf(fmaxf(wm[0], wm[1]), fmaxf(wm[2], wm[3]));
        atomicMax(gmax2, fenc(bmx));
    }
}

__global__ __launch_bounds__(256) void k_agg2(
    const int* __restrict__ bcur, const unsigned* __restrict__ pairs,
    const int* __restrict__ esrc, const int* __restrict__ edst,
    const float* __restrict__ s2, const float* __restrict__ d2, const __half* __restrict__ h2,
    const float* __restrict__ b2, const float* __restrict__ Wl1, const float* __restrict__ bl1,
    const float* __restrict__ Wl2, const float* __restrict__ bl2,
    const unsigned* __restrict__ gmax2p, float* __restrict__ out, int N, int E)
{
    __shared__ unsigned srt[SCAP];
    __shared__ float accs[HN * 17];
    __shared__ int lcnt[HN];
    __shared__ int lofs[HN + 1];
    __shared__ float dds[HN], mbs[HN];
    __shared__ float sW1[100], sb1[16], sW2[16], sb2g[16];
    __shared__ float sbl2;

    int tid = threadIdx.x;
    int fb = blockIdx.x >> 1;
    int hf = blockIdx.x & 1;
    int node0 = blockIdx.x << 6;
    if (tid < 100) sW1[tid] = Wl1[tid];
    if (tid < 16) {
        sb1[tid]  = (tid < 10) ? bl1[tid] : 0.f;
        sW2[tid]  = (tid < 10) ? Wl2[tid] : 0.f;
        sb2g[tid] = (tid < 10) ? b2[tid]  : 0.f;
    }
    if (tid == 0) sbl2 = bl2[0];
    float g0 = fdec(*gmax2p);
    if (tid < HN) {
        int n = node0 + tid;
        float dd = (n < N) ? d2[n] : 0.f;
        dds[tid] = dd; mbs[tid] = lrelu(g0 + dd);
        lcnt[tid] = 0;
    }
    __syncthreads();

    int rbase = fb * CAPB;
    int cnt = bcur[fb * 16];
    int gg = tid >> 2, q = tid & 3;

    bool ok = (cnt <= CAPB);
    unsigned pe[PESA];
    if (ok) {
#pragma unroll
        for (int u = 0; u < PESA; ++u) {
            int i = tid + u * 256;
            bool v = (i < cnt);
            pe[u] = v ? pairs[rbase + i] : 0u;
            if (v) {
                int dl = (pe[u] >> 17) & (BNODES - 1);
                if ((dl >> 6) == hf) atomicAdd(&lcnt[dl & (HN - 1)], 1);
            }
        }
        __syncthreads();
        if (tid < HN) {
            int c = lcnt[tid];
            int pfx = c;
#pragma unroll
            for (int off = 1; off < 64; off <<= 1) {
                int t = __shfl_up(pfx, off, 64);
                if (tid >= off) pfx += t;
            }
            lofs[tid + 1] = pfx;
            lcnt[tid] = pfx - c;
            if (tid == 0) lofs[0] = 0;
        }
        __syncthreads();
        if (lofs[HN] > SCAP) ok = false;
    }

    if (ok) {
#pragma unroll
        for (int u = 0; u < PESA; ++u) {
            int i = tid + u * 256;
            if (i < cnt) {
                unsigned p = pe[u];
                int dl = (p >> 17) & (BNODES - 1);
                if ((dl >> 6) == hf) {
                    int pos = atomicAdd(&lcnt[dl & (HN - 1)], 1);
                    srt[pos] = p & 0x1FFFF;
                }
            }
        }
        __syncthreads();

        int n = node0 + gg;
        float4 accv; float den;
        if (n < N) {
            float w = __expf(lrelu(s2[n] + dds[gg]) - mbs[gg]);
            float4 hv = ldh4(h2, (size_t)n * 16 + 4 * q);
            accv = make_float4(w * hv.x, w * hv.y, w * hv.z, w * hv.w);
            den = w;
        } else { accv = make_float4(0.f, 0.f, 0.f, 0.f); den = 0.f; }
        {
            float dd = dds[gg], mb = mbs[gg];
            int j = lofs[gg], j1 = lofs[gg + 1];
            for (; j + 4 <= j1; j += 4) {
                int e0 = srt[j], e1 = srt[j + 1], e2 = srt[j + 2], e3 = srt[j + 3];
                float4 H0 = ldh4(h2, (size_t)e0 * 16 + 4 * q);
                float4 H1 = ldh4(h2, (size_t)e1 * 16 + 4 * q);
                float4 H2 = ldh4(h2, (size_t)e2 * 16 + 4 * q);
                float4 H3 = ldh4(h2, (size_t)e3 * 16 + 4 * q);
                int eq = srt[j + q];
                float wq = __expf(lrelu(s2[eq] + dd) - mb);
                float w0 = __shfl(wq, 0, 4), w1 = __shfl(wq, 1, 4);
                float w2 = __shfl(wq, 2, 4), w3 = __shfl(wq, 3, 4);
                accv.x += w0 * H0.x + w1 * H1.x + w2 * H2.x + w3 * H3.x;
                accv.y += w0 * H0.y + w1 * H1.y + w2 * H2.y + w3 * H3.y;
                accv.z += w0 * H0.z + w1 * H1.z + w2 * H2.z + w3 * H3.z;
                accv.w += w0 * H0.w + w1 * H1.w + w2 * H2.w + w3 * H3.w;
                den += (w0 + w1) + (w2 + w3);
            }
            for (; j < j1; ++j) {
                int e0 = srt[j];
                float w0 = __expf(lrelu(s2[e0] + dd) - mb);
                float4 H0 = ldh4(h2, (size_t)e0 * 16 + 4 * q);
                accv.x += w0 * H0.x; accv.y += w0 * H0.y;
                accv.z += w0 * H0.z; accv.w += w0 * H0.w;
                den += w0;
            }
        }
        accs[gg * 17 + 4 * q + 0] = accv.x;
        accs[gg * 17 + 4 * q + 1] = accv.y;
        accs[gg * 17 + 4 * q + 2] = accv.z;
        accs[gg * 17 + 4 * q + 3] = accv.w;
        if (q == 0) accs[gg * 17 + 16] = den;
        __syncthreads();
    } else {
        for (int i = tid; i < HN * 17; i += 256) accs[i] = 0.f;
        __syncthreads();
        if (tid < HN) {
            int n = node0 + tid;
            if (n < N) {
                float w = __expf(lrelu(s2[n] + dds[tid]) - mbs[tid]);
#pragma unroll
                for (int t = 0; t < 16; ++t)
                    accs[tid * 17 + t] = w * __half2float(h2[(size_t)n * 16 + t]);
                accs[tid * 17 + 16] = w;
            }
        }
        __syncthreads();
        for (int i = tid; i < E; i += 256) {
            int d = edst[i];
            if ((d >> 6) != blockIdx.x) continue;
            int nl = d & (HN - 1), src = esrc[i];
            float w = __expf(lrelu(s2[src] + dds[nl]) - mbs[nl]);
#pragma unroll
            for (int t = 0; t < 16; ++t)
                atomicAdd(&accs[nl * 17 + t], w * __half2float(h2[(size_t)src * 16 + t]));
            atomicAdd(&accs[nl * 17 + 16], w);
        }
        __syncthreads();
    }

    int g = tid >> 4, k = tid & 15;
    bool fk = k < 10;
#pragma unroll
    for (int qq = 0; qq < 4; ++qq) {
        int nl = g * 4 + qq, nn = node0 + nl;
        if (nn >= N) continue;
        float inv = 1.f / accs[nl * 17 + 16];
        float o = fk ? accs[nl * 17 + k] * inv + sb2g[k] : 0.f;
        float v = sb1[k];
#pragma unroll
        for (int kk = 0; kk < 10; ++kk) {
            float ov = __shfl(o, kk, 16);
            if (fk) v += ov * sW1[kk * 10 + k];
        }
        float t = fmaxf(v, 0.f);
        float cc = t * sW2[k];
#pragma unroll
        for (int off = 1; off < 16; off <<= 1) cc += __shfl_xor(cc, off, 16);
        if (k == 0) out[nn] = cc + sbl2;
    }
}

extern "C" void kernel_launch(void* const* d_in, const int* in_sizes, int n_in,
                              void* d_out, int out_size, void* d_ws, size_t ws_size,
                              hipStream_t stream)
{
    const float* x   = (const float*)d_in[0];
    const int*   ei  = (const int*)  d_in[1];   // [2][E] int32
    const float* W1  = (const float*)d_in[2];
    const float* a1s = (const float*)d_in[3];
    const float* a1d = (const float*)d_in[4];
    const float* b1  = (const float*)d_in[5];
    const float* W2  = (const float*)d_in[6];
    const float* a2s = (const float*)d_in[7];
    const float* a2d = (const float*)d_in[8];
    const float* b2  = (const float*)d_in[9];
    const float* Wl1 = (const float*)d_in[10];
    const float* bl1 = (const float*)d_in[11];
    const float* Wl2 = (const float*)d_in[12];
    const float* bl2 = (const float*)d_in[13];

    int N = in_sizes[0] / 128;
    int E = in_sizes[1] / 2;
    const int* ei_src = ei;
    const int* ei_dst = ei + E;
    int NSB = (N + BNODES - 1) >> FSH;       // 782 buckets (<= NSBMAX)

    size_t Np = ((size_t)N + 3) & ~(size_t)3;
    size_t need_bytes = (16 + (size_t)NSB * 16) * 4 + Np * 20 * 4 + (size_t)NSB * CAPB * 4;
    if (ws_size < need_bytes) return;  // degrade to wrong-answer, never fault

    // layout: [gmax1 gmax2 pad..16][bcur NSB*16][h1 s1 d1 h2 s2 d2][pairs]
    unsigned* gmax1 = (unsigned*)d_ws;       // [0]
    unsigned* gmax2 = gmax1 + 1;             // [1]
    int* bcur = (int*)d_ws + 16;             // NSB*16 (1 cursor per 64B), RELATIVE
    float* rest = (float*)d_ws + 16 + (size_t)NSB * 16;
    __half* h1 = (__half*)rest;              // Np*16 halves
    float* s1 = rest + Np * 8;               // Np
    float* d1 = s1 + Np;                     // Np
    __half* h2 = (__half*)(d1 + Np);         // Np*16 halves (cols 10..15 zero)
    float* s2 = (float*)(h2) + Np * 8;       // Np
    float* d2 = s2 + Np;                     // Np
    unsigned* pairs = (unsigned*)(d2 + Np);  // NSB*CAPB
    float* outp = (float*)d_out;

    int NG = (N + 63) / 64;
    int NC = (E + TILE - 1) / TILE;
    int NHB = NSB * 2;

    // zero gmax + relative bucket cursors in one memset (replaces k_init)
    hipMemsetAsync(d_ws, 0, (16 + (size_t)NSB * 16) * sizeof(int), stream);
    hipLaunchKernelGGL(k_front, dim3(NG + NC), dim3(256), 0, stream,
                       x, W1, a1s, a1d, h1, s1, d1, gmax1,
                       ei_src, ei_dst, bcur, pairs, N, E, NG, NC, NSB);

    // cooperative fused agg if the whole grid fits; else legacy 2-kernel path
    bool coop = false;
    {
        int maxB = 0;
        if (hipOccupancyMaxActiveBlocksPerMultiprocessor(&maxB, k_aggf, 256, 0) == hipSuccess) {
            int dev = 0, nCU = 0;
            hipGetDevice(&dev);
            hipDeviceGetAttribute(&nCU, hipDeviceAttributeMultiprocessorCount, dev);
            if (maxB > 0 && nCU > 0 && (long long)maxB * nCU >= (long long)NHB) coop = true;
        }
    }
    if (coop) {
        const int*      a_bcur = bcur;   const unsigned* a_pairs = pairs;
        const int*      a_src  = ei_src; const int*      a_dst   = ei_dst;
        const float*    a_s1 = s1; const float* a_d1 = d1; const __half* a_h1 = h1;
        const unsigned* a_g1 = gmax1;
        void* args[] = {
            (void*)&a_bcur, (void*)&a_pairs, (void*)&a_src, (void*)&a_dst,
            (void*)&a_s1, (void*)&a_d1, (void*)&a_h1,
            (void*)&b1, (void*)&W2, (void*)&a2s, (void*)&a2d,
            (void*)&h2, (void*)&s2, (void*)&d2,
            (void*)&a_g1, (void*)&gmax2,
            (void*)&b2, (void*)&Wl1, (void*)&bl1, (void*)&Wl2, (void*)&bl2,
            (void*)&outp, (void*)&N, (void*)&E
        };
        hipError_t e = hipLaunchCooperativeKernel((const void*)k_aggf, dim3(NHB), dim3(256),
                                                  args, 0, stream);
        if (e != hipSuccess) coop = false;
    }
    if (!coop) {
        hipLaunchKernelGGL(k_agg1, dim3(NHB), dim3(256), 0, stream,
                           bcur, pairs, ei_src, ei_dst, s1, d1, h1, b1, W2, a2s, a2d,
                           h2, s2, d2, gmax1, gmax2, N, E);
        hipLaunchKernelGGL(k_agg2, dim3(NHB), dim3(256), 0, stream,
                           bcur, pairs, ei_src, ei_dst, s2, d2, h2, b2, Wl1, bl1, Wl2, bl2,
                           gmax2, (float*)d_out, N, E);
    }
}

// Round 7
// 263.508 us; speedup vs baseline: 1.0839x; 1.0412x over previous
//
#include <hip/hip_runtime.h>
#include <hip/hip_fp16.h>

// GAT (2 layers, heads=1) + 2-layer MLP head. N=100000, E=3200000, D=128.
// R22 = R20 front + R11 full-bucket aggs with SORT REUSE:
//  - agg1 (512 thr/bucket) builds the dst-sorted srt/lofs as before, then
//    writes the sorted srcs back IN-PLACE over its pairs region (it has
//    fully consumed the region into registers first) and lofs -> lofs_g.
//  - agg2 is sort-free: loads lofs_g + the sorted region (coalesced LDS
//    copy, no atomics/scan), then gather + MLP epilogue.
// R21 lesson: cooperative launch is not graph-capturable (fallback ran);
// the coop kernel was also 4x slower (register-capped gather). Dropped.
// Overflow -> full-rescan fallback keeps arbitrary inputs correct.
// Softmax stabilization uses a GLOBAL upper bound m̄_i = leaky(gmax_asrc+adst_i)
// (valid since leaky_relu is monotone); alpha is mathematically unchanged.

#define NEG 0.2f
#define FSH 7
#define BNODES 128           // nodes per bucket
#define NSBMAX 1024          // >= ceil(100000/128)=782
#define CAPB 4608            // per-bucket region capacity (mean 4096, +8 sigma)
#define TILE 4096            // edges per csplit block (256 threads, 16/thread)
#define EPT 16               // TILE/256 register-staged edges per thread
#define PES 9                // ceil(CAPB/512) register-staged pairs per thread
#define LOFSTR 132           // lofs_g stride per bucket (129 lofs + flag + pad)

__device__ __forceinline__ float lrelu(float x) { return x > 0.0f ? x : NEG * x; }

__device__ __forceinline__ unsigned fenc(float f) {
    unsigned u = __float_as_uint(f);
    return (u & 0x80000000u) ? ~u : (u | 0x80000000u);
}
__device__ __forceinline__ float fdec(unsigned e) {
    return (e & 0x80000000u) ? __uint_as_float(e & 0x7FFFFFFFu) : __uint_as_float(~e);
}

// load 4 consecutive halves as float4 (8B load)
__device__ __forceinline__ float4 ldh4(const __half* h, size_t off) {
    uint2 u = *(const uint2*)(h + off);
    __half2 a = *(__half2*)&u.x, b = *(__half2*)&u.y;
    float2 fa = __half22float2(a), fb = __half22float2(b);
    return make_float4(fa.x, fa.y, fb.x, fb.y);
}

// ---- fused front-end: gemm role + csplit role in one grid (R20) ----
__global__ __launch_bounds__(256) void k_front(
    const float* __restrict__ x, const float* __restrict__ W1,
    const float* __restrict__ a1s, const float* __restrict__ a1d,
    __half* __restrict__ h1, float* __restrict__ s1, float* __restrict__ d1,
    unsigned* __restrict__ gmax,
    const int* __restrict__ esrc, const int* __restrict__ edst,
    int* __restrict__ bcur, unsigned* __restrict__ pairs,
    int N, int E, int NG, int NC, int NSB)
{
    __shared__ float smem[9220];
    int tid = threadIdx.x;
    int bid = blockIdx.x;
    long long T = (long long)NG + NC;
    int before = (int)(((long long)bid * NC) / T);
    int isc = (int)((((long long)bid + 1) * NC) / T) > before;

    if (isc) {
        unsigned* lsrt = (unsigned*)smem;                   // TILE
        int* lhist = (int*)smem + TILE;                     // 1024
        int* lofs  = lhist + NSBMAX;                        // 1024
        int* gbase = lofs + NSBMAX;                         // 1024
        int* wsum  = gbase + NSBMAX;                        // 4
        unsigned short* rid = (unsigned short*)(smem + TILE + 3 * NSBMAX + 4);
        int cid = before;
        int base = cid * TILE;
        int tcnt = min(TILE, E - base);
        for (int i = tid; i < NSB; i += 256) lhist[i] = 0;
        __syncthreads();
        int ed[EPT];
#pragma unroll
        for (int u = 0; u < EPT; ++u) {
            int i = tid + u * 256;
            ed[u] = (i < tcnt) ? edst[base + i] : -1;
            if (ed[u] >= 0) atomicAdd(&lhist[ed[u] >> FSH], 1);
        }
        __syncthreads();
        int i0 = 4 * tid;
        int a0 = (i0 + 0 < NSB) ? lhist[i0 + 0] : 0;
        int a1 = (i0 + 1 < NSB) ? lhist[i0 + 1] : 0;
        int a2 = (i0 + 2 < NSB) ? lhist[i0 + 2] : 0;
        int a3 = (i0 + 3 < NSB) ? lhist[i0 + 3] : 0;
        int s = a0 + a1 + a2 + a3, pfx = s;
#pragma unroll
        for (int off = 1; off < 64; off <<= 1) {
            int t = __shfl_up(pfx, off, 64);
            if ((tid & 63) >= off) pfx += t;
        }
        if ((tid & 63) == 63) wsum[tid >> 6] = pfx;
        __syncthreads();
        int carry = 0;
        for (int w = 0; w < (tid >> 6); ++w) carry += wsum[w];
        int excl = pfx + carry - s;
        if (i0 + 0 < NSB) { lofs[i0 + 0] = excl;                 gbase[i0 + 0] = a0 ? atomicAdd(&bcur[(i0 + 0) * 16], a0) : 0; }
        if (i0 + 1 < NSB) { lofs[i0 + 1] = excl + a0;            gbase[i0 + 1] = a1 ? atomicAdd(&bcur[(i0 + 1) * 16], a1) : 0; }
        if (i0 + 2 < NSB) { lofs[i0 + 2] = excl + a0 + a1;       gbase[i0 + 2] = a2 ? atomicAdd(&bcur[(i0 + 2) * 16], a2) : 0; }
        if (i0 + 3 < NSB) { lofs[i0 + 3] = excl + a0 + a1 + a2;  gbase[i0 + 3] = a3 ? atomicAdd(&bcur[(i0 + 3) * 16], a3) : 0; }
        __syncthreads();
        if (i0 + 0 < NSB) lhist[i0 + 0] = lofs[i0 + 0];
        if (i0 + 1 < NSB) lhist[i0 + 1] = lofs[i0 + 1];
        if (i0 + 2 < NSB) lhist[i0 + 2] = lofs[i0 + 2];
        if (i0 + 3 < NSB) lhist[i0 + 3] = lofs[i0 + 3];
        __syncthreads();
#pragma unroll
        for (int u = 0; u < EPT; ++u) {
            int i = tid + u * 256;
            if (ed[u] >= 0) {
                int d = ed[u], srcv = esrc[base + i];
                int b = d >> FSH;
                int pos = atomicAdd(&lhist[b], 1);
                lsrt[pos] = ((unsigned)(d & (BNODES - 1)) << 17) | (unsigned)srcv;
                rid[pos] = (unsigned short)b;
            }
        }
        __syncthreads();
        for (int i = tid; i < tcnt; i += 256) {
            int r = rid[i];
            int rel = gbase[r] + (i - lofs[r]);
            if (rel < CAPB) pairs[(size_t)r * CAPB + rel] = lsrt[i];
        }
        return;
    }

    // gemm role (no x stage; j-partitioned lanes)
    float* sW = smem;
    float* wm = smem + 2060;
    int gid = bid - before;
    for (int i = tid; i < 2048; i += 256) sW[i + ((i >> 9) << 2)] = W1[i];
    int node0 = gid * 64;
    int node = node0 + (tid >> 2);
    int q = tid & 3;
    bool valid = node < N;
    float4 xr[8];
    {
        const float4* xp = (const float4*)x + (size_t)node * 32 + q * 8;
#pragma unroll
        for (int k = 0; k < 8; ++k)
            xr[k] = valid ? xp[k] : make_float4(0.f, 0.f, 0.f, 0.f);
    }
    __syncthreads();

    float acc[16];
#pragma unroll
    for (int c = 0; c < 16; ++c) acc[c] = 0.f;
    int wbase = q * 516;
#pragma unroll
    for (int k = 0; k < 8; ++k) {
        float xs0 = xr[k].x, xs1 = xr[k].y, xs2 = xr[k].z, xs3 = xr[k].w;
#pragma unroll
        for (int t = 0; t < 4; ++t) {
            float xv = (t == 0) ? xs0 : (t == 1) ? xs1 : (t == 2) ? xs2 : xs3;
            const float4* wrow = (const float4*)&sW[wbase + (k * 4 + t) * 16];
            float4 w0 = wrow[0], w1 = wrow[1], w2 = wrow[2], w3 = wrow[3];
            acc[0]  += xv * w0.x; acc[1]  += xv * w0.y; acc[2]  += xv * w0.z; acc[3]  += xv * w0.w;
            acc[4]  += xv * w1.x; acc[5]  += xv * w1.y; acc[6]  += xv * w1.z; acc[7]  += xv * w1.w;
            acc[8]  += xv * w2.x; acc[9]  += xv * w2.y; acc[10] += xv * w2.z; acc[11] += xv * w2.w;
            acc[12] += xv * w3.x; acc[13] += xv * w3.y; acc[14] += xv * w3.z; acc[15] += xv * w3.w;
        }
    }
#pragma unroll
    for (int c = 0; c < 16; ++c) {
        acc[c] += __shfl_xor(acc[c], 1);
        acc[c] += __shfl_xor(acc[c], 2);
    }
    float sv = 0.f, dv = 0.f;
    {
        const float4* asp = (const float4*)a1s;
        const float4* adp = (const float4*)a1d;
#pragma unroll
        for (int r = 0; r < 4; ++r) {
            float4 as = asp[r], ad = adp[r];
            sv += acc[r*4+0]*as.x + acc[r*4+1]*as.y + acc[r*4+2]*as.z + acc[r*4+3]*as.w;
            dv += acc[r*4+0]*ad.x + acc[r*4+1]*ad.y + acc[r*4+2]*ad.z + acc[r*4+3]*ad.w;
        }
    }
    if (valid) {
        float4 av;
        if      (q == 0) av = make_float4(acc[0],  acc[1],  acc[2],  acc[3]);
        else if (q == 1) av = make_float4(acc[4],  acc[5],  acc[6],  acc[7]);
        else if (q == 2) av = make_float4(acc[8],  acc[9],  acc[10], acc[11]);
        else             av = make_float4(acc[12], acc[13], acc[14], acc[15]);
        __half2 p0 = __floats2half2_rn(av.x, av.y);
        __half2 p1 = __floats2half2_rn(av.z, av.w);
        uint2 u; u.x = *(unsigned*)&p0; u.y = *(unsigned*)&p1;
        *(uint2*)&h1[(size_t)node * 16 + q * 4] = u;
        if (q == 0) { s1[node] = sv; d1[node] = dv; }
    }
    float m = valid ? sv : -3.4e38f;
#pragma unroll
    for (int off = 32; off >= 1; off >>= 1) m = fmaxf(m, __shfl_xor(m, off));
    if ((tid & 63) == 0) wm[tid >> 6] = m;
    __syncthreads();
    if (tid == 0) {
        float b = fmaxf(fmaxf(wm[0], wm[1]), fmaxf(wm[2], wm[3]));
        atomicMax(gmax, fenc(b));
    }
}

// ---- layer-1 agg: R11 full-bucket sort+gather, plus sorted write-back ----
__global__ __launch_bounds__(512) void k_agg1(
    const int* __restrict__ bcur, unsigned* __restrict__ pairs,
    const int* __restrict__ esrc, const int* __restrict__ edst,
    const float* __restrict__ s1, const float* __restrict__ d1, const __half* __restrict__ h1,
    const float* __restrict__ b1, const float* __restrict__ W2,
    const float* __restrict__ a2s, const float* __restrict__ a2d,
    __half* __restrict__ h2, float* __restrict__ s2, float* __restrict__ d2,
    const unsigned* __restrict__ gmax1p, unsigned* __restrict__ gmax2,
    int* __restrict__ lofs_g, int N, int E)
{
    __shared__ unsigned srt[CAPB];
    __shared__ float accs[BNODES * 17];
    __shared__ int lcnt[BNODES];
    __shared__ int lofs[BNODES + 1];
    __shared__ float dds[BNODES], mbs[BNODES];
    __shared__ float sW[160], sb[16], sas[16], sad[16];
    __shared__ int wsum[8];
    __shared__ float wm[8];

    int tid = threadIdx.x;
    int fb = blockIdx.x;
    if (tid < 160) sW[tid] = W2[tid];
    if (tid < 16) {
        sb[tid]  = b1[tid];
        sas[tid] = (tid < 10) ? a2s[tid] : 0.f;
        sad[tid] = (tid < 10) ? a2d[tid] : 0.f;
    }
    int node0 = fb << FSH;
    float g0 = fdec(*gmax1p);
    if (tid < BNODES) {
        int n = node0 + tid;
        float dd = (n < N) ? d1[n] : 0.f;
        dds[tid] = dd; mbs[tid] = lrelu(g0 + dd);
        lcnt[tid] = 0;
    }
    __syncthreads();

    int rbase = fb * CAPB;
    int cnt = bcur[fb * 16];             // RELATIVE count; > CAPB means overflow
    int gg = tid >> 2, q = tid & 3;      // 128 groups x 4 lanes, 1 node each

    if (cnt <= CAPB) {
        // count pass with register staging (single global read of pairs)
        unsigned pe[PES];
#pragma unroll
        for (int u = 0; u < PES; ++u) {
            int i = tid + u * 512;
            bool ok = (i < cnt);
            pe[u] = ok ? pairs[rbase + i] : 0u;
            if (ok) atomicAdd(&lcnt[(pe[u] >> 17) & (BNODES - 1)], 1);
        }
        __syncthreads();
        // 128-key scan (padded to 512 threads)
        int c = (tid < BNODES) ? lcnt[tid] : 0;
        int pfx = c;
#pragma unroll
        for (int off = 1; off < 64; off <<= 1) {
            int t = __shfl_up(pfx, off, 64);
            if ((tid & 63) >= off) pfx += t;
        }
        if ((tid & 63) == 63) wsum[tid >> 6] = pfx;
        __syncthreads();
        int carry = 0;
        for (int w = 0; w < (tid >> 6); ++w) carry += wsum[w];
        pfx += carry;
        if (tid < BNODES) { lofs[tid + 1] = pfx; lcnt[tid] = pfx - c; }
        if (tid == 0) lofs[0] = 0;
        __syncthreads();
        // scatter pass from registers -> dst-sorted srcs
#pragma unroll
        for (int u = 0; u < PES; ++u) {
            int i = tid + u * 512;
            if (i < cnt) {
                unsigned p = pe[u];
                int pos = atomicAdd(&lcnt[(p >> 17) & (BNODES - 1)], 1);
                srt[pos] = p & 0x1FFFF;
            }
        }
        __syncthreads();

        // write-back sorted srcs over own region + lofs for the sort-free agg2
#pragma unroll
        for (int u = 0; u < PES; ++u) {
            int i = tid + u * 512;
            if (i < cnt) pairs[rbase + i] = srt[i];
        }
        if (tid <= BNODES) lofs_g[fb * LOFSTR + tid] = lofs[tid];
        if (tid == 0) lofs_g[fb * LOFSTR + BNODES + 1] = 1;

        // self-loop init + register gather (1 exp/edge via width-4 shfl)
        int n = node0 + gg;
        float4 accv; float den;
        if (n < N) {
            float w = __expf(lrelu(s1[n] + dds[gg]) - mbs[gg]);
            float4 hv = ldh4(h1, (size_t)n * 16 + 4 * q);
            accv = make_float4(w * hv.x, w * hv.y, w * hv.z, w * hv.w);
            den = w;
        } else { accv = make_float4(0.f, 0.f, 0.f, 0.f); den = 0.f; }
        {
            float dd = dds[gg], mb = mbs[gg];
            int j = lofs[gg], j1 = lofs[gg + 1];
            for (; j + 4 <= j1; j += 4) {
                int e0 = srt[j], e1 = srt[j + 1], e2 = srt[j + 2], e3 = srt[j + 3];
                float4 H0 = ldh4(h1, (size_t)e0 * 16 + 4 * q);
                float4 H1 = ldh4(h1, (size_t)e1 * 16 + 4 * q);
                float4 H2 = ldh4(h1, (size_t)e2 * 16 + 4 * q);
                float4 H3 = ldh4(h1, (size_t)e3 * 16 + 4 * q);
                int eq = srt[j + q];
                float wq = __expf(lrelu(s1[eq] + dd) - mb);
                float w0 = __shfl(wq, 0, 4), w1 = __shfl(wq, 1, 4);
                float w2 = __shfl(wq, 2, 4), w3 = __shfl(wq, 3, 4);
                accv.x += w0 * H0.x + w1 * H1.x + w2 * H2.x + w3 * H3.x;
                accv.y += w0 * H0.y + w1 * H1.y + w2 * H2.y + w3 * H3.y;
                accv.z += w0 * H0.z + w1 * H1.z + w2 * H2.z + w3 * H3.z;
                accv.w += w0 * H0.w + w1 * H1.w + w2 * H2.w + w3 * H3.w;
                den += (w0 + w1) + (w2 + w3);
            }
            for (; j < j1; ++j) {
                int e0 = srt[j];
                float w0 = __expf(lrelu(s1[e0] + dd) - mb);
                float4 H0 = ldh4(h1, (size_t)e0 * 16 + 4 * q);
                accv.x += w0 * H0.x; accv.y += w0 * H0.y;
                accv.z += w0 * H0.z; accv.w += w0 * H0.w;
                den += w0;
            }
        }
        // stage accumulators to LDS (stride-17 rows)
        accs[gg * 17 + 4 * q + 0] = accv.x;
        accs[gg * 17 + 4 * q + 1] = accv.y;
        accs[gg * 17 + 4 * q + 2] = accv.z;
        accs[gg * 17 + 4 * q + 3] = accv.w;
        if (q == 0) accs[gg * 17 + 16] = den;
        __syncthreads();
    } else {
        // overflow: region incomplete -> full rescan of source edges (never-path)
        if (tid == 0) lofs_g[fb * LOFSTR + BNODES + 1] = 0;
        for (int i = tid; i < BNODES * 17; i += 512) accs[i] = 0.f;
        __syncthreads();
        if (tid < BNODES) {
            int n = node0 + tid;
            if (n < N) {
                float w = __expf(lrelu(s1[n] + dds[tid]) - mbs[tid]);
#pragma unroll
                for (int t = 0; t < 16; ++t)
                    accs[tid * 17 + t] = w * __half2float(h1[(size_t)n * 16 + t]);
                accs[tid * 17 + 16] = w;
            }
        }
        __syncthreads();
        for (int i = tid; i < E; i += 512) {
            int d = edst[i];
            if ((d >> FSH) != fb) continue;
            int nl = d & (BNODES - 1), src = esrc[i];
            float w = __expf(lrelu(s1[src] + dds[nl]) - mbs[nl]);
#pragma unroll
            for (int t = 0; t < 16; ++t)
                atomicAdd(&accs[nl * 17 + t], w * __half2float(h1[(size_t)src * 16 + t]));
            atomicAdd(&accs[nl * 17 + 16], w);
        }
        __syncthreads();
    }

    // epilogue: 32 groups of 16 lanes, 4 nodes each
    int g = tid >> 4, k = tid & 15;
    float sval = -3.4e38f;
#pragma unroll
    for (int qq = 0; qq < 4; ++qq) {
        int nl = g * 4 + qq, nn = node0 + nl;
        if (nn >= N) continue;           // group-uniform
        float inv = 1.f / accs[nl * 17 + 16];
        float o = fmaxf(accs[nl * 17 + k] * inv + sb[k], 0.f);
        float hh = 0.f;
#pragma unroll
        for (int kk = 0; kk < 16; ++kk) {
            float ov = __shfl(o, kk, 16);
            if (k < 10) hh += ov * sW[kk * 10 + k];
        }
        if (k >= 10) hh = 0.f;
        float ts = hh * sas[k];
        float td = hh * sad[k];
#pragma unroll
        for (int off = 1; off < 16; off <<= 1) {
            ts += __shfl_xor(ts, off, 16);
            td += __shfl_xor(td, off, 16);
        }
        h2[(size_t)nn * 16 + k] = __float2half_rn(hh);  // zero-padded cols 10..15
        if (k == 0) { s2[nn] = ts; d2[nn] = td; }
        sval = fmaxf(sval, ts);
    }
    float m = sval;
#pragma unroll
    for (int off = 32; off >= 1; off >>= 1) m = fmaxf(m, __shfl_xor(m, off));
    if ((tid & 63) == 0) wm[tid >> 6] = m;
    __syncthreads();
    if (tid == 0) {
        float bmx = wm[0];
#pragma unroll
        for (int i = 1; i < 8; ++i) bmx = fmaxf(bmx, wm[i]);
        atomicMax(gmax2, fenc(bmx));
    }
}

// ---- layer-2 agg: SORT-FREE (reads agg1's sorted region + lofs_g) ----
__global__ __launch_bounds__(512) void k_agg2(
    const unsigned* __restrict__ pairs,
    const int* __restrict__ esrc, const int* __restrict__ edst,
    const float* __restrict__ s2, const float* __restrict__ d2, const __half* __restrict__ h2,
    const float* __restrict__ b2, const float* __restrict__ Wl1, const float* __restrict__ bl1,
    const float* __restrict__ Wl2, const float* __restrict__ bl2,
    const unsigned* __restrict__ gmax2p, const int* __restrict__ lofs_g,
    float* __restrict__ out, int N, int E)
{
    __shared__ unsigned srt[CAPB];
    __shared__ float accs[BNODES * 17];
    __shared__ int lofs[BNODES + 1];
    __shared__ float dds[BNODES], mbs[BNODES];
    __shared__ float sW1[100], sb1[16], sW2[16], sb2g[16];
    __shared__ float sbl2;
    __shared__ int s_ok;

    int tid = threadIdx.x;
    int fb = blockIdx.x;
    if (tid < 100) sW1[tid] = Wl1[tid];
    if (tid < 16) {
        sb1[tid]  = (tid < 10) ? bl1[tid] : 0.f;
        sW2[tid]  = (tid < 10) ? Wl2[tid] : 0.f;
        sb2g[tid] = (tid < 10) ? b2[tid]  : 0.f;
    }
    if (tid == 0) sbl2 = bl2[0];
    if (tid <= BNODES) lofs[tid] = lofs_g[fb * LOFSTR + tid];
    if (tid == 256) s_ok = lofs_g[fb * LOFSTR + BNODES + 1];
    int node0 = fb << FSH;
    float g0 = fdec(*gmax2p);
    if (tid < BNODES) {
        int n = node0 + tid;
        float dd = (n < N) ? d2[n] : 0.f;
        dds[tid] = dd; mbs[tid] = lrelu(g0 + dd);
    }
    __syncthreads();

    int rbase = fb * CAPB;
    int gg = tid >> 2, q = tid & 3;

    if (s_ok) {
        // coalesced copy of the pre-sorted srcs into LDS (no atomics/scan)
        int cnt = lofs[BNODES];
#pragma unroll
        for (int u = 0; u < PES; ++u) {
            int i = tid + u * 512;
            if (i < cnt) srt[i] = pairs[rbase + i];
        }
        __syncthreads();

        int n = node0 + gg;
        float4 accv; float den;
        if (n < N) {
            float w = __expf(lrelu(s2[n] + dds[gg]) - mbs[gg]);
            float4 hv = ldh4(h2, (size_t)n * 16 + 4 * q);   // zero-padded
            accv = make_float4(w * hv.x, w * hv.y, w * hv.z, w * hv.w);
            den = w;
        } else { accv = make_float4(0.f, 0.f, 0.f, 0.f); den = 0.f; }
        {
            float dd = dds[gg], mb = mbs[gg];
            int j = lofs[gg], j1 = lofs[gg + 1];
            for (; j + 4 <= j1; j += 4) {
                int e0 = srt[j], e1 = srt[j + 1], e2 = srt[j + 2], e3 = srt[j + 3];
                float4 H0 = ldh4(h2, (size_t)e0 * 16 + 4 * q);
                float4 H1 = ldh4(h2, (size_t)e1 * 16 + 4 * q);
                float4 H2 = ldh4(h2, (size_t)e2 * 16 + 4 * q);
                float4 H3 = ldh4(h2, (size_t)e3 * 16 + 4 * q);
                int eq = srt[j + q];
                float wq = __expf(lrelu(s2[eq] + dd) - mb);
                float w0 = __shfl(wq, 0, 4), w1 = __shfl(wq, 1, 4);
                float w2 = __shfl(wq, 2, 4), w3 = __shfl(wq, 3, 4);
                accv.x += w0 * H0.x + w1 * H1.x + w2 * H2.x + w3 * H3.x;
                accv.y += w0 * H0.y + w1 * H1.y + w2 * H2.y + w3 * H3.y;
                accv.z += w0 * H0.z + w1 * H1.z + w2 * H2.z + w3 * H3.z;
                accv.w += w0 * H0.w + w1 * H1.w + w2 * H2.w + w3 * H3.w;
                den += (w0 + w1) + (w2 + w3);
            }
            for (; j < j1; ++j) {
                int e0 = srt[j];
                float w0 = __expf(lrelu(s2[e0] + dd) - mb);
                float4 H0 = ldh4(h2, (size_t)e0 * 16 + 4 * q);
                accv.x += w0 * H0.x; accv.y += w0 * H0.y;
                accv.z += w0 * H0.z; accv.w += w0 * H0.w;
                den += w0;
            }
        }
        accs[gg * 17 + 4 * q + 0] = accv.x;
        accs[gg * 17 + 4 * q + 1] = accv.y;
        accs[gg * 17 + 4 * q + 2] = accv.z;
        accs[gg * 17 + 4 * q + 3] = accv.w;
        if (q == 0) accs[gg * 17 + 16] = den;
        __syncthreads();
    } else {
        for (int i = tid; i < BNODES * 17; i += 512) accs[i] = 0.f;
        __syncthreads();
        if (tid < BNODES) {
            int n = node0 + tid;
            if (n < N) {
                float w = __expf(lrelu(s2[n] + dds[tid]) - mbs[tid]);
#pragma unroll
                for (int t = 0; t < 16; ++t)
                    accs[tid * 17 + t] = w * __half2float(h2[(size_t)n * 16 + t]);
                accs[tid * 17 + 16] = w;
            }
        }
        __syncthreads();
        for (int i = tid; i < E; i += 512) {
            int d = edst[i];
            if ((d >> FSH) != fb) continue;
            int nl = d & (BNODES - 1), src = esrc[i];
            float w = __expf(lrelu(s2[src] + dds[nl]) - mbs[nl]);
#pragma unroll
            for (int t = 0; t < 16; ++t)
                atomicAdd(&accs[nl * 17 + t], w * __half2float(h2[(size_t)src * 16 + t]));
            atomicAdd(&accs[nl * 17 + 16], w);
        }
        __syncthreads();
    }

    int g = tid >> 4, k = tid & 15;
    bool fk = k < 10;
#pragma unroll
    for (int qq = 0; qq < 4; ++qq) {
        int nl = g * 4 + qq, nn = node0 + nl;
        if (nn >= N) continue;           // group-uniform
        float inv = 1.f / accs[nl * 17 + 16];
        float o = fk ? accs[nl * 17 + k] * inv + sb2g[k] : 0.f;
        float v = sb1[k];
#pragma unroll
        for (int kk = 0; kk < 10; ++kk) {
            float ov = __shfl(o, kk, 16);
            if (fk) v += ov * sW1[kk * 10 + k];
        }
        float t = fmaxf(v, 0.f);
        float cc = t * sW2[k];           // zero for k>=10
#pragma unroll
        for (int off = 1; off < 16; off <<= 1) cc += __shfl_xor(cc, off, 16);
        if (k == 0) out[nn] = cc + sbl2;
    }
}

extern "C" void kernel_launch(void* const* d_in, const int* in_sizes, int n_in,
                              void* d_out, int out_size, void* d_ws, size_t ws_size,
                              hipStream_t stream)
{
    const float* x   = (const float*)d_in[0];
    const int*   ei  = (const int*)  d_in[1];   // [2][E] int32
    const float* W1  = (const float*)d_in[2];
    const float* a1s = (const float*)d_in[3];
    const float* a1d = (const float*)d_in[4];
    const float* b1  = (const float*)d_in[5];
    const float* W2  = (const float*)d_in[6];
    const float* a2s = (const float*)d_in[7];
    const float* a2d = (const float*)d_in[8];
    const float* b2  = (const float*)d_in[9];
    const float* Wl1 = (const float*)d_in[10];
    const float* bl1 = (const float*)d_in[11];
    const float* Wl2 = (const float*)d_in[12];
    const float* bl2 = (const float*)d_in[13];

    int N = in_sizes[0] / 128;
    int E = in_sizes[1] / 2;
    const int* ei_src = ei;
    const int* ei_dst = ei + E;
    int NSB = (N + BNODES - 1) >> FSH;       // 782 buckets (<= NSBMAX)

    size_t Np = ((size_t)N + 3) & ~(size_t)3;
    size_t need_bytes = (16 + (size_t)NSB * 16) * 4 + Np * 20 * 4
                      + (size_t)NSB * CAPB * 4 + (size_t)NSB * LOFSTR * 4;
    if (ws_size < need_bytes) return;  // degrade to wrong-answer, never fault

    // layout: [gmax1 gmax2 pad..16][bcur NSB*16][h1 s1 d1 h2 s2 d2][pairs][lofs_g]
    unsigned* gmax1 = (unsigned*)d_ws;       // [0]
    unsigned* gmax2 = gmax1 + 1;             // [1]
    int* bcur = (int*)d_ws + 16;             // NSB*16 (1 cursor per 64B), RELATIVE
    float* rest = (float*)d_ws + 16 + (size_t)NSB * 16;
    __half* h1 = (__half*)rest;              // Np*16 halves
    float* s1 = rest + Np * 8;               // Np
    float* d1 = s1 + Np;                     // Np
    __half* h2 = (__half*)(d1 + Np);         // Np*16 halves (cols 10..15 zero)
    float* s2 = (float*)(h2) + Np * 8;       // Np
    float* d2 = s2 + Np;                     // Np
    unsigned* pairs = (unsigned*)(d2 + Np);  // NSB*CAPB
    int* lofs_g = (int*)(pairs + (size_t)NSB * CAPB);  // NSB*LOFSTR

    int NG = (N + 63) / 64;
    int NC = (E + TILE - 1) / TILE;

    // zero gmax + relative bucket cursors in one memset (replaces k_init)
    hipMemsetAsync(d_ws, 0, (16 + (size_t)NSB * 16) * sizeof(int), stream);
    hipLaunchKernelGGL(k_front, dim3(NG + NC), dim3(256), 0, stream,
                       x, W1, a1s, a1d, h1, s1, d1, gmax1,
                       ei_src, ei_dst, bcur, pairs, N, E, NG, NC, NSB);
    hipLaunchKernelGGL(k_agg1, dim3(NSB), dim3(512), 0, stream,
                       bcur, pairs, ei_src, ei_dst, s1, d1, h1, b1, W2, a2s, a2d,
                       h2, s2, d2, gmax1, gmax2, lofs_g, N, E);
    hipLaunchKernelGGL(k_agg2, dim3(NSB), dim3(512), 0, stream,
                       pairs, ei_src, ei_dst, s2, d2, h2, b2, Wl1, bl1, Wl2, bl2,
                       gmax2, lofs_g, (float*)d_out, N, E);
}